// Round 4
// baseline (209.575 us; speedup 1.0000x reference)
//
#include <hip/hip_runtime.h>
#include <hip/hip_bf16.h>
#include <stdint.h>

typedef __attribute__((ext_vector_type(8))) short bf16x8;
typedef __attribute__((ext_vector_type(4))) float f32x4;
typedef __attribute__((ext_vector_type(16))) float f32x16;
typedef __attribute__((ext_vector_type(4))) unsigned int u32x4;

#define MFMA16(a, b, c) __builtin_amdgcn_mfma_f32_16x16x32_bf16(a, b, c, 0, 0, 0)
#define MFMA32(a, b, c) __builtin_amdgcn_mfma_f32_32x32x16_bf16(a, b, c, 0, 0, 0)

constexpr float QSCALE = 0.04419417382415922f * 1.4426950408889634f;  // 1/sqrt(512) * log2(e)

__device__ __forceinline__ void gload_lds16(const void* g, void* l) {
  __builtin_amdgcn_global_load_lds((const __attribute__((address_space(1))) uint32_t*)g,
                                   (__attribute__((address_space(3))) uint32_t*)l, 16, 0, 0);
}
__device__ __forceinline__ bf16x8 lds_read_swz(const short* base, int row, int ch) {
  return *(const bf16x8*)((const char*)base + row * 128 + (((ch ^ row) & 7) << 4));
}
__device__ __forceinline__ short f2b(float f) {
  __hip_bfloat16 h = __float2bfloat16(f);
  return *reinterpret_cast<short*>(&h);
}
__device__ __forceinline__ float exp2fast(float x) {
#if __has_builtin(__builtin_amdgcn_exp2f)
  return __builtin_amdgcn_exp2f(x);
#else
  return exp2f(x);
#endif
}

// ---------------- converters ----------------
__global__ void k_cvt_x(const float* __restrict__ x, short* __restrict__ xb) {
  const int i = blockIdx.x * 256 + threadIdx.x;
  const float4 v = ((const float4*)x)[i];
  short4 o;
  o.x = f2b(v.x); o.y = f2b(v.y); o.z = f2b(v.z); o.w = f2b(v.w);
  ((short4*)xb)[i] = o;
}

// wt[mat][n][k] = bf16(W_mat[k][n]) ; mat: 0=Wq 1=Wk 2=Wv 3=Wo
__global__ void k_cvt_w(const float* __restrict__ wq, const float* __restrict__ wk,
                        const float* __restrict__ wv, const float* __restrict__ wo,
                        short* __restrict__ wt) {
  const int gid = blockIdx.x * 256 + threadIdx.x;
  const int mat = gid >> 18;
  const int idx = gid & 262143;
  const int n = idx >> 9, k = idx & 511;
  const float* w = (mat == 0) ? wq : (mat == 1) ? wk : (mat == 2) ? wv : wo;
  wt[gid] = f2b(w[k * 512 + n]);
}

// ---------------- prefix-scan of kept keys (mask==0) ----------------
__global__ void k_scan(const int* __restrict__ mask, int* __restrict__ perm,
                       int* __restrict__ cnt) {
  __shared__ int ws[16];
  const int b = blockIdx.x, tid = threadIdx.x;  // 1024 threads
  const int lane = tid & 63, w = tid >> 6;
  const int* m = mask + b * 4096;
  int v[4], s = 0;
#pragma unroll
  for (int j = 0; j < 4; ++j) { v[j] = (m[tid * 4 + j] == 0) ? 1 : 0; s += v[j]; }
  int sc = s;
  for (int d = 1; d < 64; d <<= 1) { int t = __shfl_up(sc, d); if (lane >= d) sc += t; }
  if (lane == 63) ws[w] = sc;
  __syncthreads();
  if (tid == 0) {
    int acc = 0;
    for (int i = 0; i < 16; ++i) { int t = ws[i]; ws[i] = acc; acc += t; }
    cnt[b] = acc;
  }
  __syncthreads();
  int pos = ws[w] + sc - s;
  int* p = perm + b * 4096;
#pragma unroll
  for (int j = 0; j < 4; ++j) { p[tid * 4 + j] = v[j] ? pos : -1; pos += v[j]; }
}

// ---------------- 128x128-tile GEMM (m97 structure) ----------------
// MODE 0: A = x_bf16 [8192][512]; W = wt (Q|K|V stacked, n-major [1536][512]).
//   grid (64, 12). Epilogue scatters into fragment-packed Q'/K'/V' workspaces.
// MODE 1: A = attn_out bf16; W = Wo' [512][512]; fo = f32 out. grid (64, 4).
template <int MODE>
__global__ __launch_bounds__(256, 2) void k_gemm2(
    const short* __restrict__ A, const short* __restrict__ W,
    const float* __restrict__ bq, const float* __restrict__ bk,
    const float* __restrict__ bv, const int* __restrict__ perm,
    short* __restrict__ oq, short* __restrict__ ok, short* __restrict__ ov,
    float* __restrict__ fo) {
  __shared__ short Asm[2][128 * 64];
  __shared__ short Bsm[2][128 * 64];
  const int tid = threadIdx.x;
  const int wave = tid >> 6, lane = tid & 63;
  const int lane15 = lane & 15, g = lane >> 4;
  const int wm = wave >> 1, wn = wave & 1;
  const int m0 = blockIdx.x * 128;
  const int n0 = blockIdx.y * 128;

  const char* Ag = (const char*)A + (size_t)m0 * 1024;
  const char* Bg = (const char*)W + (size_t)n0 * 1024;

  f32x4 acc[4][4] = {};

  auto stage = [&](int buf, int kt) {
    const int k0b = kt * 128;
#pragma unroll
    for (int q = 0; q < 4; ++q) {
      int s_ = (wave * 4 + q) * 64 + lane;
      int row = s_ >> 3, ch = s_ & 7;
      gload_lds16(Ag + (size_t)row * 1024 + k0b + (((ch ^ row) & 7) << 4),
                  (char*)&Asm[buf][0] + s_ * 16);
      gload_lds16(Bg + (size_t)row * 1024 + k0b + (((ch ^ row) & 7) << 4),
                  (char*)&Bsm[buf][0] + s_ * 16);
    }
  };

  stage(0, 0);
  asm volatile("s_waitcnt vmcnt(0)" ::: "memory");
  __syncthreads();

  for (int kt = 0; kt < 8; ++kt) {
    const int cur = kt & 1;
    if (kt < 7) stage(cur ^ 1, kt + 1);
#pragma unroll
    for (int kk = 0; kk < 2; ++kk) {
      bf16x8 af[4], bfr[4];
#pragma unroll
      for (int m = 0; m < 4; ++m)
        af[m] = lds_read_swz(&Asm[cur][0], wm * 64 + m * 16 + lane15, kk * 4 + g);
#pragma unroll
      for (int n = 0; n < 4; ++n)
        bfr[n] = lds_read_swz(&Bsm[cur][0], wn * 64 + n * 16 + lane15, kk * 4 + g);
      __builtin_amdgcn_s_setprio(1);
#pragma unroll
      for (int m = 0; m < 4; ++m)
#pragma unroll
        for (int n = 0; n < 4; ++n)
          acc[m][n] = MFMA16(af[m], bfr[n], acc[m][n]);
      __builtin_amdgcn_s_setprio(0);
    }
    asm volatile("s_waitcnt vmcnt(0)" ::: "memory");
    __syncthreads();
  }

#pragma unroll
  for (int nf = 0; nf < 4; ++nf) {
    const int col = n0 + wn * 64 + nf * 16 + lane15;
    if constexpr (MODE == 0) {
      const int mat = col >> 9, nn = col & 511;
      const int hh = nn >> 6, d = nn & 63;
      const float bias = ((mat == 0) ? bq : (mat == 1) ? bk : bv)[nn];
      const int dk = d >> 4, hb = (d >> 3) & 1, jj = d & 7;
#pragma unroll
      for (int mf = 0; mf < 4; ++mf) {
#pragma unroll
        for (int j = 0; j < 4; ++j) {
          const int rowg = m0 + wm * 64 + mf * 16 + g * 4 + j;
          const int b_ = rowg >> 12, sl = rowg & 4095;
          const size_t bh = (size_t)(b_ * 8 + hh);
          const float v = acc[mf][nf][j] + bias;
          if (mat == 0) {
            oq[bh * 262144 +
               (size_t)(((sl >> 5) * 4 + dk) * 64 + hb * 32 + (sl & 31)) * 8 + jj] =
                f2b(v * QSCALE);
          } else {
            const int pm_ = perm[b_ * 4096 + sl];
            if (pm_ >= 0) {
              const int t = pm_ >> 6, r = pm_ & 63;
              if (mat == 1) {
                ok[bh * 262144 +
                   (size_t)((t * 8 + dk * 2 + (r >> 5)) * 64 + hb * 32 + (r & 31)) * 8 + jj] =
                    f2b(v);
              } else {
                const int mm = (r & ~12) | (((r >> 2) & 1) << 3) | (((r >> 3) & 1) << 2);
                ov[bh * 262144 +
                   (size_t)((t * 8 + ((mm >> 4) & 3) * 2 + (d >> 5)) * 64 +
                            ((mm >> 3) & 1) * 32 + (d & 31)) * 8 + (mm & 7)] = f2b(v);
              }
            }
          }
        }
      }
    } else {
      const float bias = bq[col];
#pragma unroll
      for (int mf = 0; mf < 4; ++mf)
#pragma unroll
        for (int j = 0; j < 4; ++j) {
          const int rowg = m0 + wm * 64 + mf * 16 + g * 4 + j;
          fo[(size_t)rowg * 512 + col] = acc[mf][nf][j] + bias;
        }
    }
  }
}

// ---------------- flash attention, split-KV, no LDS/barriers ----------------
#define ATT_BODY(T, KC, KN)                                                   \
  {                                                                           \
    bf16x8 v0_ = vld(T, 0), v1_ = vld(T, 1), v2_ = vld(T, 2), v3_ = vld(T, 3),\
           v4_ = vld(T, 4), v5_ = vld(T, 5), v6_ = vld(T, 6), v7_ = vld(T, 7);\
    f32x16 s0v = {}, s1v = {};                                                \
    __builtin_amdgcn_s_setprio(1);                                            \
    _Pragma("unroll") for (int dk = 0; dk < 4; ++dk) {                        \
      s0v = MFMA32(KC[2 * dk], qreg[dk], s0v);                                \
      s1v = MFMA32(KC[2 * dk + 1], qreg[dk], s1v);                            \
    }                                                                         \
    __builtin_amdgcn_s_setprio(0);                                            \
    _Pragma("unroll") for (int u = 0; u < 8; ++u) KN[u] = kld((T) + 1, u);    \
    if ((T) == nt - 1 && lim < 64) {                                          \
      _Pragma("unroll") for (int i = 0; i < 16; ++i) {                        \
        const int r0 = (i & 3) + 8 * (i >> 2) + 4 * h;                        \
        if (r0 >= lim) s0v[i] = -1e30f;                                       \
        if (r0 + 32 >= lim) s1v[i] = -1e30f;                                  \
      }                                                                       \
    }                                                                         \
    float pm = s0v[0];                                                        \
    _Pragma("unroll") for (int i = 1; i < 16; ++i) pm = fmaxf(pm, s0v[i]);    \
    _Pragma("unroll") for (int i = 0; i < 16; ++i) pm = fmaxf(pm, s1v[i]);    \
    pm = fmaxf(pm, __shfl_xor(pm, 32));                                       \
    if (__any(pm > m_ + 8.f)) {                                               \
      const float nm = fmaxf(m_, pm);                                         \
      const float sc = exp2fast(m_ - nm);                                     \
      m_ = nm; l_ *= sc; o0 = o0 * sc; o1 = o1 * sc;                          \
    }                                                                         \
    unsigned int wA[8], wB[8];                                                \
    float ts = 0.f;                                                           \
    _Pragma("unroll") for (int j2 = 0; j2 < 8; ++j2) {                        \
      float a0 = exp2fast(s0v[2 * j2] - m_);                                  \
      float a1 = exp2fast(s0v[2 * j2 + 1] - m_);                              \
      float b0 = exp2fast(s1v[2 * j2] - m_);                                  \
      float b1 = exp2fast(s1v[2 * j2 + 1] - m_);                              \
      ts += (a0 + a1) + (b0 + b1);                                            \
      asm("v_cvt_pk_bf16_f32 %0, %1, %2" : "=v"(wA[j2]) : "v"(a0), "v"(a1));  \
      asm("v_cvt_pk_bf16_f32 %0, %1, %2" : "=v"(wB[j2]) : "v"(b0), "v"(b1));  \
    }                                                                         \
    ts += __shfl_xor(ts, 32);                                                 \
    l_ += ts;                                                                 \
    __builtin_amdgcn_s_setprio(1);                                            \
    {                                                                         \
      union PU { u32x4 u; bf16x8 f; } pu;                                     \
      pu.u[0] = wA[0]; pu.u[1] = wA[1]; pu.u[2] = wA[2]; pu.u[3] = wA[3];     \
      o0 = MFMA32(v0_, pu.f, o0); o1 = MFMA32(v1_, pu.f, o1);                 \
      pu.u[0] = wA[4]; pu.u[1] = wA[5]; pu.u[2] = wA[6]; pu.u[3] = wA[7];     \
      o0 = MFMA32(v2_, pu.f, o0); o1 = MFMA32(v3_, pu.f, o1);                 \
      pu.u[0] = wB[0]; pu.u[1] = wB[1]; pu.u[2] = wB[2]; pu.u[3] = wB[3];     \
      o0 = MFMA32(v4_, pu.f, o0); o1 = MFMA32(v5_, pu.f, o1);                 \
      pu.u[0] = wB[4]; pu.u[1] = wB[5]; pu.u[2] = wB[6]; pu.u[3] = wB[7];     \
      o0 = MFMA32(v6_, pu.f, o0); o1 = MFMA32(v7_, pu.f, o1);                 \
    }                                                                         \
    __builtin_amdgcn_s_setprio(0);                                            \
  }

__global__ __launch_bounds__(256, 2) void k_attn(
    const short* __restrict__ Qp, const short* __restrict__ Kp,
    const short* __restrict__ Vp, const int* __restrict__ cnt,
    float* __restrict__ Op, float* __restrict__ Ml) {
  const int tid = threadIdx.x;
  const int wave = tid >> 6, lane = tid & 63;
  const int l31 = lane & 31, h = lane >> 5;
  const int bh = blockIdx.y, b = bh >> 3;
  const int z = blockIdx.z;
  const int qb = blockIdx.x * 4 + wave;  // 32-row q-block index (0..127)

  const short* Qg = Qp + (size_t)bh * 262144;
  const short* Kg = Kp + (size_t)bh * 262144;
  const short* Vg = Vp + (size_t)bh * 262144;

  auto kld = [&](int t, int u) {
    return *(const bf16x8*)(Kg + ((size_t)(t * 8 + u) * 64 + lane) * 8);
  };
  auto vld = [&](int t, int u) {
    return *(const bf16x8*)(Vg + ((size_t)(t * 8 + u) * 64 + lane) * 8);
  };

  bf16x8 qreg[4];
#pragma unroll
  for (int dk = 0; dk < 4; ++dk)
    qreg[dk] = *(const bf16x8*)(Qg + ((size_t)(qb * 4 + dk) * 64 + lane) * 8);

  const int cn = cnt[b];
  const int nt = max(1, (cn + 63) >> 6);
  const int lim = cn - (nt - 1) * 64;  // keys in last tile (0..64)
  const int half = (nt + 1) >> 1;
  const int t0 = z ? half : 0;
  const int t1 = z ? nt : half;

  bf16x8 ka[8], kb[8];
  f32x16 o0 = {}, o1 = {};
  float m_ = -1.0e30f, l_ = 0.f;

  if (t0 < t1) {
#pragma unroll
    for (int u = 0; u < 8; ++u) ka[u] = kld(t0, u);
    for (int t = t0; t < t1; t += 2) {
      ATT_BODY(t, ka, kb);
      if (t + 1 < t1) ATT_BODY(t + 1, kb, ka);
    }
  }

  float* ob = Op + ((size_t)(z * 16 + bh) * 128 + qb) * 2048 + lane * 32;
  union OU { f32x16 v; float f[16]; } u0, u1;
  u0.v = o0; u1.v = o1;
#pragma unroll
  for (int i = 0; i < 16; ++i) ob[i] = u0.f[i];
#pragma unroll
  for (int i = 0; i < 16; ++i) ob[16 + i] = u1.f[i];
  if (h == 0) {
    float2 ml; ml.x = m_; ml.y = l_;
    ((float2*)Ml)[((size_t)(z * 16 + bh) * 128 + qb) * 32 + l31] = ml;
  }
}

// ---------------- combine 2 KV-splits -> normalized bf16 attn out ----------------
__global__ __launch_bounds__(256, 4) void k_comb(
    const float* __restrict__ Op, const float* __restrict__ Ml,
    short* __restrict__ out) {
  const int tid = threadIdx.x;
  const int wave = tid >> 6, lane = tid & 63;
  const int l31 = lane & 31, h = lane >> 5;
  const int bh = blockIdx.y, b = bh >> 3, hh = bh & 7;
  const int qb = blockIdx.x * 4 + wave;

  const float2 ml0 = ((const float2*)Ml)[((size_t)(0 * 16 + bh) * 128 + qb) * 32 + l31];
  const float2 ml1 = ((const float2*)Ml)[((size_t)(1 * 16 + bh) * 128 + qb) * 32 + l31];
  const float nm = fmaxf(ml0.x, ml1.x);
  const float w0 = exp2fast(ml0.x - nm), w1 = exp2fast(ml1.x - nm);
  const float inv = 1.0f / (w0 * ml0.y + w1 * ml1.y);
  const float a0 = w0 * inv, a1 = w1 * inv;

  const float* p0 = Op + ((size_t)(0 * 16 + bh) * 128 + qb) * 2048 + lane * 32;
  const float* p1 = Op + ((size_t)(1 * 16 + bh) * 128 + qb) * 2048 + lane * 32;
  float r[32];
#pragma unroll
  for (int i = 0; i < 8; ++i) {
    const float4 x0 = ((const float4*)p0)[i];
    const float4 x1 = ((const float4*)p1)[i];
    r[4 * i + 0] = x0.x * a0 + x1.x * a1;
    r[4 * i + 1] = x0.y * a0 + x1.y * a1;
    r[4 * i + 2] = x0.z * a0 + x1.z * a1;
    r[4 * i + 3] = x0.w * a0 + x1.w * a1;
  }

  short* og = out + (size_t)(b * 4096 + qb * 32 + l31) * 512 + hh * 64;
#pragma unroll
  for (int r2 = 0; r2 < 4; ++r2) {
    {
      const int base = 8 * r2 + 4 * h;
      short4 s4;
      s4.x = f2b(r[4 * r2 + 0]);
      s4.y = f2b(r[4 * r2 + 1]);
      s4.z = f2b(r[4 * r2 + 2]);
      s4.w = f2b(r[4 * r2 + 3]);
      *(short4*)(og + base) = s4;
    }
    {
      const int base = 32 + 8 * r2 + 4 * h;
      short4 s4;
      s4.x = f2b(r[16 + 4 * r2 + 0]);
      s4.y = f2b(r[16 + 4 * r2 + 1]);
      s4.z = f2b(r[16 + 4 * r2 + 2]);
      s4.w = f2b(r[16 + 4 * r2 + 3]);
      *(short4*)(og + base) = s4;
    }
  }
}

// ---------------- launch ----------------
extern "C" void kernel_launch(void* const* d_in, const int* in_sizes, int n_in,
                              void* d_out, int out_size, void* d_ws, size_t ws_size,
                              hipStream_t stream) {
  const float* x  = (const float*)d_in[0];
  const int* mask = (const int*)d_in[1];
  const float* Wq = (const float*)d_in[2];
  const float* bq = (const float*)d_in[3];
  const float* Wk = (const float*)d_in[4];
  const float* bk = (const float*)d_in[5];
  const float* Wv = (const float*)d_in[6];
  const float* bv = (const float*)d_in[7];
  const float* Wo = (const float*)d_in[8];
  const float* bo = (const float*)d_in[9];
  float* out = (float*)d_out;

  short* xb   = (short*)d_ws;                        // 8192*512 bf16
  short* wt   = xb + (size_t)8192 * 512;             // 4*512*512 bf16
  short* qws  = wt + (size_t)4 * 512 * 512;          // Q' fragment-packed, QSCALE'd
  short* kws  = qws + (size_t)8192 * 512;            // K' fragment-packed, compacted
  short* vws  = kws + (size_t)8192 * 512;            // V' fragment-packed, compacted+bitswap
  short* aout = vws + (size_t)8192 * 512;            // [b*s][512] bf16
  float* opart = (float*)(aout + (size_t)8192 * 512);  // [2][16][128][2048] f32
  float* mlp   = opart + (size_t)2 * 16 * 128 * 2048;  // [2][16][128][32] float2
  int* perm   = (int*)(mlp + (size_t)2 * 16 * 128 * 32 * 2);
  int* cntw   = perm + 8192;

  k_cvt_x<<<4096, 256, 0, stream>>>(x, xb);
  k_cvt_w<<<4096, 256, 0, stream>>>(Wq, Wk, Wv, Wo, wt);
  k_scan<<<2, 1024, 0, stream>>>(mask, perm, cntw);
  k_gemm2<0><<<dim3(64, 12), 256, 0, stream>>>(xb, wt, bq, bk, bv, perm,
                                               qws, kws, vws, nullptr);
  k_attn<<<dim3(32, 16, 2), 256, 0, stream>>>(qws, kws, vws, cntw, opart, mlp);
  k_comb<<<dim3(32, 16), 256, 0, stream>>>(opart, mlp, aout);
  k_gemm2<1><<<dim3(64, 4), 256, 0, stream>>>(aout, wt + (size_t)3 * 512 * 512, bo,
                                              nullptr, nullptr, nullptr,
                                              nullptr, nullptr, nullptr, out);
}

// Round 5
// 184.783 us; speedup vs baseline: 1.1342x; 1.1342x over previous
//
#include <hip/hip_runtime.h>
#include <hip/hip_bf16.h>
#include <stdint.h>

typedef __attribute__((ext_vector_type(8))) short bf16x8;
typedef __attribute__((ext_vector_type(4))) float f32x4;
typedef __attribute__((ext_vector_type(16))) float f32x16;
typedef __attribute__((ext_vector_type(4))) unsigned int u32x4;

#define MFMA16(a, b, c) __builtin_amdgcn_mfma_f32_16x16x32_bf16(a, b, c, 0, 0, 0)
#define MFMA32(a, b, c) __builtin_amdgcn_mfma_f32_32x32x16_bf16(a, b, c, 0, 0, 0)

constexpr float QSCALE = 0.04419417382415922f * 1.4426950408889634f;  // 1/sqrt(512) * log2(e)

__device__ __forceinline__ void gload_lds16(const void* g, void* l) {
  __builtin_amdgcn_global_load_lds((const __attribute__((address_space(1))) uint32_t*)g,
                                   (__attribute__((address_space(3))) uint32_t*)l, 16, 0, 0);
}
__device__ __forceinline__ bf16x8 lds_read_swz(const short* base, int row, int ch) {
  return *(const bf16x8*)((const char*)base + row * 128 + (((ch ^ row) & 7) << 4));
}
__device__ __forceinline__ short f2b(float f) {
  __hip_bfloat16 h = __float2bfloat16(f);
  return *reinterpret_cast<short*>(&h);
}
__device__ __forceinline__ float exp2fast(float x) {
#if __has_builtin(__builtin_amdgcn_exp2f)
  return __builtin_amdgcn_exp2f(x);
#else
  return exp2f(x);
#endif
}

// ---------------- converters ----------------
__global__ void k_cvt_x(const float* __restrict__ x, short* __restrict__ xb) {
  const int i = blockIdx.x * 256 + threadIdx.x;
  const float4 v = ((const float4*)x)[i];
  short4 o;
  o.x = f2b(v.x); o.y = f2b(v.y); o.z = f2b(v.z); o.w = f2b(v.w);
  ((short4*)xb)[i] = o;
}

// wt[mat][n][k] = bf16(W_mat[k][n]) ; mat: 0=Wq 1=Wk 2=Wv 3=Wo
__global__ void k_cvt_w(const float* __restrict__ wq, const float* __restrict__ wk,
                        const float* __restrict__ wv, const float* __restrict__ wo,
                        short* __restrict__ wt) {
  const int gid = blockIdx.x * 256 + threadIdx.x;
  const int mat = gid >> 18;
  const int idx = gid & 262143;
  const int n = idx >> 9, k = idx & 511;
  const float* w = (mat == 0) ? wq : (mat == 1) ? wk : (mat == 2) ? wv : wo;
  wt[gid] = f2b(w[k * 512 + n]);
}

// ---------------- prefix-scan of kept keys (mask==0) ----------------
__global__ void k_scan(const int* __restrict__ mask, int* __restrict__ perm,
                       int* __restrict__ cnt) {
  __shared__ int ws[16];
  const int b = blockIdx.x, tid = threadIdx.x;  // 1024 threads
  const int lane = tid & 63, w = tid >> 6;
  const int* m = mask + b * 4096;
  int v[4], s = 0;
#pragma unroll
  for (int j = 0; j < 4; ++j) { v[j] = (m[tid * 4 + j] == 0) ? 1 : 0; s += v[j]; }
  int sc = s;
  for (int d = 1; d < 64; d <<= 1) { int t = __shfl_up(sc, d); if (lane >= d) sc += t; }
  if (lane == 63) ws[w] = sc;
  __syncthreads();
  if (tid == 0) {
    int acc = 0;
    for (int i = 0; i < 16; ++i) { int t = ws[i]; ws[i] = acc; acc += t; }
    cnt[b] = acc;
  }
  __syncthreads();
  int pos = ws[w] + sc - s;
  int* p = perm + b * 4096;
#pragma unroll
  for (int j = 0; j < 4; ++j) { p[tid * 4 + j] = v[j] ? pos : -1; pos += v[j]; }
}

// ---------------- 128x128-tile GEMM (m97 structure) ----------------
// MODE 0: A = x_bf16 [8192][512]; W = wt (Q|K|V stacked, n-major [1536][512]).
//   grid (64, 12). Epilogue scatters into fragment-packed Q'/K'/V' workspaces.
// MODE 1: A = attn_out bf16; W = Wo' [512][512]; fo = f32 out. grid (64, 4).
template <int MODE>
__global__ __launch_bounds__(256, 2) void k_gemm2(
    const short* __restrict__ A, const short* __restrict__ W,
    const float* __restrict__ bq, const float* __restrict__ bk,
    const float* __restrict__ bv, const int* __restrict__ perm,
    short* __restrict__ oq, short* __restrict__ ok, short* __restrict__ ov,
    float* __restrict__ fo) {
  __shared__ short Asm[2][128 * 64];
  __shared__ short Bsm[2][128 * 64];
  const int tid = threadIdx.x;
  const int wave = tid >> 6, lane = tid & 63;
  const int lane15 = lane & 15, g = lane >> 4;
  const int wm = wave >> 1, wn = wave & 1;
  const int m0 = blockIdx.x * 128;
  const int n0 = blockIdx.y * 128;

  const char* Ag = (const char*)A + (size_t)m0 * 1024;
  const char* Bg = (const char*)W + (size_t)n0 * 1024;

  f32x4 acc[4][4] = {};

  auto stage = [&](int buf, int kt) {
    const int k0b = kt * 128;
#pragma unroll
    for (int q = 0; q < 4; ++q) {
      int s_ = (wave * 4 + q) * 64 + lane;
      int row = s_ >> 3, ch = s_ & 7;
      gload_lds16(Ag + (size_t)row * 1024 + k0b + (((ch ^ row) & 7) << 4),
                  (char*)&Asm[buf][0] + s_ * 16);
      gload_lds16(Bg + (size_t)row * 1024 + k0b + (((ch ^ row) & 7) << 4),
                  (char*)&Bsm[buf][0] + s_ * 16);
    }
  };

  stage(0, 0);
  asm volatile("s_waitcnt vmcnt(0)" ::: "memory");
  __syncthreads();

  for (int kt = 0; kt < 8; ++kt) {
    const int cur = kt & 1;
    if (kt < 7) stage(cur ^ 1, kt + 1);
#pragma unroll
    for (int kk = 0; kk < 2; ++kk) {
      bf16x8 af[4], bfr[4];
#pragma unroll
      for (int m = 0; m < 4; ++m)
        af[m] = lds_read_swz(&Asm[cur][0], wm * 64 + m * 16 + lane15, kk * 4 + g);
#pragma unroll
      for (int n = 0; n < 4; ++n)
        bfr[n] = lds_read_swz(&Bsm[cur][0], wn * 64 + n * 16 + lane15, kk * 4 + g);
      __builtin_amdgcn_s_setprio(1);
#pragma unroll
      for (int m = 0; m < 4; ++m)
#pragma unroll
        for (int n = 0; n < 4; ++n)
          acc[m][n] = MFMA16(af[m], bfr[n], acc[m][n]);
      __builtin_amdgcn_s_setprio(0);
    }
    asm volatile("s_waitcnt vmcnt(0)" ::: "memory");
    __syncthreads();
  }

#pragma unroll
  for (int nf = 0; nf < 4; ++nf) {
    const int col = n0 + wn * 64 + nf * 16 + lane15;
    if constexpr (MODE == 0) {
      const int mat = col >> 9, nn = col & 511;
      const int hh = nn >> 6, d = nn & 63;
      const float bias = ((mat == 0) ? bq : (mat == 1) ? bk : bv)[nn];
      const int dk = d >> 4, hb = (d >> 3) & 1, jj = d & 7;
#pragma unroll
      for (int mf = 0; mf < 4; ++mf) {
#pragma unroll
        for (int j = 0; j < 4; ++j) {
          const int rowg = m0 + wm * 64 + mf * 16 + g * 4 + j;
          const int b_ = rowg >> 12, sl = rowg & 4095;
          const size_t bh = (size_t)(b_ * 8 + hh);
          const float v = acc[mf][nf][j] + bias;
          if (mat == 0) {
            oq[bh * 262144 +
               (size_t)(((sl >> 5) * 4 + dk) * 64 + hb * 32 + (sl & 31)) * 8 + jj] =
                f2b(v * QSCALE);
          } else {
            const int pm_ = perm[b_ * 4096 + sl];
            if (pm_ >= 0) {
              const int t = pm_ >> 6, r = pm_ & 63;
              if (mat == 1) {
                ok[bh * 262144 +
                   (size_t)((t * 8 + dk * 2 + (r >> 5)) * 64 + hb * 32 + (r & 31)) * 8 + jj] =
                    f2b(v);
              } else {
                const int mm = (r & ~12) | (((r >> 2) & 1) << 3) | (((r >> 3) & 1) << 2);
                ov[bh * 262144 +
                   (size_t)((t * 8 + ((mm >> 4) & 3) * 2 + (d >> 5)) * 64 +
                            ((mm >> 3) & 1) * 32 + (d & 31)) * 8 + (mm & 7)] = f2b(v);
              }
            }
          }
        }
      }
    } else {
      const float bias = bq[col];
#pragma unroll
      for (int mf = 0; mf < 4; ++mf)
#pragma unroll
        for (int j = 0; j < 4; ++j) {
          const int rowg = m0 + wm * 64 + mf * 16 + g * 4 + j;
          fo[(size_t)rowg * 512 + col] = acc[mf][nf][j] + bias;
        }
    }
  }
}

// ---------------- flash attention: fixed-base softmax, no LDS, no barriers ----------
// grid (32, 16); 4 independent waves/block, 32 q-rows each; KV tiles of 64 compacted keys.
// QK^T = mfma(K, Q) -> score col = q = lane&31. Scores are hard-bounded (C-S: |s|<33),
// so p = exp2(s) never overflows f32 and the softmax shift cancels in o/l. No max
// tracking, no rescale, no per-tile cross-lane ops: l is a per-lane sum, reduced once.
// PV = mfma(V', P) -> O col = q ; V' key order bit-swapped so P is lane-local.
#define ATT_BODY(T, KC, KN)                                                   \
  {                                                                           \
    bf16x8 v0_ = vld(T, 0), v1_ = vld(T, 1), v2_ = vld(T, 2), v3_ = vld(T, 3),\
           v4_ = vld(T, 4), v5_ = vld(T, 5), v6_ = vld(T, 6), v7_ = vld(T, 7);\
    f32x16 s0v = {}, s1v = {};                                                \
    __builtin_amdgcn_s_setprio(1);                                            \
    _Pragma("unroll") for (int dk = 0; dk < 4; ++dk) {                        \
      s0v = MFMA32(KC[2 * dk], qreg[dk], s0v);                                \
      s1v = MFMA32(KC[2 * dk + 1], qreg[dk], s1v);                            \
    }                                                                         \
    __builtin_amdgcn_s_setprio(0);                                            \
    _Pragma("unroll") for (int u = 0; u < 8; ++u) KN[u] = kld((T) + 1, u);    \
    if ((T) == nt - 1 && lim < 64) {                                          \
      _Pragma("unroll") for (int i = 0; i < 16; ++i) {                        \
        const int r0 = (i & 3) + 8 * (i >> 2) + 4 * h;                        \
        if (r0 >= lim) s0v[i] = -1e30f;                                       \
        if (r0 + 32 >= lim) s1v[i] = -1e30f;                                  \
      }                                                                       \
    }                                                                         \
    unsigned int wA[8], wB[8];                                                \
    float ts = 0.f;                                                           \
    _Pragma("unroll") for (int j2 = 0; j2 < 8; ++j2) {                        \
      float a0 = exp2fast(s0v[2 * j2]);                                       \
      float a1 = exp2fast(s0v[2 * j2 + 1]);                                   \
      float b0 = exp2fast(s1v[2 * j2]);                                       \
      float b1 = exp2fast(s1v[2 * j2 + 1]);                                   \
      ts += (a0 + a1) + (b0 + b1);                                            \
      asm("v_cvt_pk_bf16_f32 %0, %1, %2" : "=v"(wA[j2]) : "v"(a0), "v"(a1));  \
      asm("v_cvt_pk_bf16_f32 %0, %1, %2" : "=v"(wB[j2]) : "v"(b0), "v"(b1));  \
    }                                                                         \
    l_ += ts;                                                                 \
    __builtin_amdgcn_s_setprio(1);                                            \
    {                                                                         \
      union PU { u32x4 u; bf16x8 f; } pu;                                     \
      pu.u[0] = wA[0]; pu.u[1] = wA[1]; pu.u[2] = wA[2]; pu.u[3] = wA[3];     \
      o0 = MFMA32(v0_, pu.f, o0); o1 = MFMA32(v1_, pu.f, o1);                 \
      pu.u[0] = wA[4]; pu.u[1] = wA[5]; pu.u[2] = wA[6]; pu.u[3] = wA[7];     \
      o0 = MFMA32(v2_, pu.f, o0); o1 = MFMA32(v3_, pu.f, o1);                 \
      pu.u[0] = wB[0]; pu.u[1] = wB[1]; pu.u[2] = wB[2]; pu.u[3] = wB[3];     \
      o0 = MFMA32(v4_, pu.f, o0); o1 = MFMA32(v5_, pu.f, o1);                 \
      pu.u[0] = wB[4]; pu.u[1] = wB[5]; pu.u[2] = wB[6]; pu.u[3] = wB[7];     \
      o0 = MFMA32(v6_, pu.f, o0); o1 = MFMA32(v7_, pu.f, o1);                 \
    }                                                                         \
    __builtin_amdgcn_s_setprio(0);                                            \
  }

__global__ __launch_bounds__(256, 2) void k_attn(
    const short* __restrict__ Qp, const short* __restrict__ Kp,
    const short* __restrict__ Vp, const int* __restrict__ cnt,
    short* __restrict__ out) {
  const int tid = threadIdx.x;
  const int wave = tid >> 6, lane = tid & 63;
  const int l31 = lane & 31, h = lane >> 5;
  const int bh = blockIdx.y, b = bh >> 3, hh = bh & 7;
  const int qb = blockIdx.x * 4 + wave;  // 32-row q-block index

  const short* Qg = Qp + (size_t)bh * 262144;
  const short* Kg = Kp + (size_t)bh * 262144;
  const short* Vg = Vp + (size_t)bh * 262144;

  auto kld = [&](int t, int u) {
    return *(const bf16x8*)(Kg + ((size_t)(t * 8 + u) * 64 + lane) * 8);
  };
  auto vld = [&](int t, int u) {
    return *(const bf16x8*)(Vg + ((size_t)(t * 8 + u) * 64 + lane) * 8);
  };

  bf16x8 qreg[4];
#pragma unroll
  for (int dk = 0; dk < 4; ++dk)
    qreg[dk] = *(const bf16x8*)(Qg + ((size_t)(qb * 4 + dk) * 64 + lane) * 8);

  const int cn = cnt[b];
  const int nt = max(1, (cn + 63) >> 6);
  const int lim = cn - (nt - 1) * 64;  // keys in last tile (0..64)

  bf16x8 ka[8], kb[8];
#pragma unroll
  for (int u = 0; u < 8; ++u) ka[u] = kld(0, u);

  f32x16 o0 = {}, o1 = {};
  float l_ = 0.f;

  for (int t = 0; t < nt; t += 2) {
    ATT_BODY(t, ka, kb);
    if (t + 1 < nt) ATT_BODY(t + 1, kb, ka);
  }

  l_ += __shfl_xor(l_, 32);
  const float inv = 1.0f / l_;
  short* og = out + (size_t)(b * 4096 + qb * 32 + l31) * 512 + hh * 64;
#pragma unroll
  for (int r2 = 0; r2 < 4; ++r2) {
    {
      const int base = 8 * r2 + 4 * h;
      short4 s4;
      s4.x = f2b(o0[4 * r2 + 0] * inv);
      s4.y = f2b(o0[4 * r2 + 1] * inv);
      s4.z = f2b(o0[4 * r2 + 2] * inv);
      s4.w = f2b(o0[4 * r2 + 3] * inv);
      *(short4*)(og + base) = s4;
    }
    {
      const int base = 32 + 8 * r2 + 4 * h;
      short4 s4;
      s4.x = f2b(o1[4 * r2 + 0] * inv);
      s4.y = f2b(o1[4 * r2 + 1] * inv);
      s4.z = f2b(o1[4 * r2 + 2] * inv);
      s4.w = f2b(o1[4 * r2 + 3] * inv);
      *(short4*)(og + base) = s4;
    }
  }
}

// ---------------- launch ----------------
extern "C" void kernel_launch(void* const* d_in, const int* in_sizes, int n_in,
                              void* d_out, int out_size, void* d_ws, size_t ws_size,
                              hipStream_t stream) {
  const float* x  = (const float*)d_in[0];
  const int* mask = (const int*)d_in[1];
  const float* Wq = (const float*)d_in[2];
  const float* bq = (const float*)d_in[3];
  const float* Wk = (const float*)d_in[4];
  const float* bk = (const float*)d_in[5];
  const float* Wv = (const float*)d_in[6];
  const float* bv = (const float*)d_in[7];
  const float* Wo = (const float*)d_in[8];
  const float* bo = (const float*)d_in[9];
  float* out = (float*)d_out;

  short* xb   = (short*)d_ws;                        // 8192*512 bf16
  short* wt   = xb + (size_t)8192 * 512;             // 4*512*512 bf16
  short* qws  = wt + (size_t)4 * 512 * 512;          // Q' fragment-packed, QSCALE'd
  short* kws  = qws + (size_t)8192 * 512;            // K' fragment-packed, compacted
  short* vws  = kws + (size_t)8192 * 512;            // V' fragment-packed, compacted+bitswap
  short* aout = vws + (size_t)8192 * 512;            // [b*s][512] bf16
  int* perm   = (int*)(aout + (size_t)8192 * 512);   // [b][s]
  int* cntw   = perm + 8192;

  k_cvt_x<<<4096, 256, 0, stream>>>(x, xb);
  k_cvt_w<<<4096, 256, 0, stream>>>(Wq, Wk, Wv, Wo, wt);
  k_scan<<<2, 1024, 0, stream>>>(mask, perm, cntw);
  k_gemm2<0><<<dim3(64, 12), 256, 0, stream>>>(xb, wt, bq, bk, bv, perm,
                                               qws, kws, vws, nullptr);
  k_attn<<<dim3(32, 16), 256, 0, stream>>>(qws, kws, vws, cntw, aout);
  k_gemm2<1><<<dim3(64, 4), 256, 0, stream>>>(aout, wt + (size_t)3 * 512 * 512, bo,
                                              nullptr, nullptr, nullptr,
                                              nullptr, nullptr, nullptr, out);
}

// Round 7
// 180.442 us; speedup vs baseline: 1.1615x; 1.0241x over previous
//
#include <hip/hip_runtime.h>
#include <hip/hip_bf16.h>
#include <stdint.h>

typedef __attribute__((ext_vector_type(8))) short bf16x8;
typedef __attribute__((ext_vector_type(4))) float f32x4;
typedef __attribute__((ext_vector_type(16))) float f32x16;
typedef __attribute__((ext_vector_type(4))) unsigned int u32x4;

#define MFMA16(a, b, c) __builtin_amdgcn_mfma_f32_16x16x32_bf16(a, b, c, 0, 0, 0)
#define MFMA32(a, b, c) __builtin_amdgcn_mfma_f32_32x32x16_bf16(a, b, c, 0, 0, 0)

constexpr float QSCALE = 0.04419417382415922f * 1.4426950408889634f;  // 1/sqrt(512) * log2(e)

__device__ __forceinline__ void gload_lds16(const void* g, void* l) {
  __builtin_amdgcn_global_load_lds((const __attribute__((address_space(1))) uint32_t*)g,
                                   (__attribute__((address_space(3))) uint32_t*)l, 16, 0, 0);
}
__device__ __forceinline__ bf16x8 lds_read_swz(const short* base, int row, int ch) {
  return *(const bf16x8*)((const char*)base + row * 128 + (((ch ^ row) & 7) << 4));
}
__device__ __forceinline__ short f2b(float f) {
  __hip_bfloat16 h = __float2bfloat16(f);
  return *reinterpret_cast<short*>(&h);
}
__device__ __forceinline__ float exp2fast(float x) {
#if __has_builtin(__builtin_amdgcn_exp2f)
  return __builtin_amdgcn_exp2f(x);
#else
  return exp2f(x);
#endif
}

// ---------------- converters ----------------
__global__ void k_cvt_x(const float* __restrict__ x, short* __restrict__ xb) {
  const int i = blockIdx.x * 256 + threadIdx.x;
  const float4 v = ((const float4*)x)[i];
  short4 o;
  o.x = f2b(v.x); o.y = f2b(v.y); o.z = f2b(v.z); o.w = f2b(v.w);
  ((short4*)xb)[i] = o;
}

// wt[mat][n][k] = bf16(W_mat[k][n]) ; mat: 0=Wq 1=Wk 2=Wv 3=Wo
__global__ void k_cvt_w(const float* __restrict__ wq, const float* __restrict__ wk,
                        const float* __restrict__ wv, const float* __restrict__ wo,
                        short* __restrict__ wt) {
  const int gid = blockIdx.x * 256 + threadIdx.x;
  const int mat = gid >> 18;
  const int idx = gid & 262143;
  const int n = idx >> 9, k = idx & 511;
  const float* w = (mat == 0) ? wq : (mat == 1) ? wk : (mat == 2) ? wv : wo;
  wt[gid] = f2b(w[k * 512 + n]);
}

// ---------------- prefix-scan of kept keys (mask==0) ----------------
__global__ void k_scan(const int* __restrict__ mask, int* __restrict__ perm,
                       int* __restrict__ cnt) {
  __shared__ int ws[16];
  const int b = blockIdx.x, tid = threadIdx.x;  // 1024 threads
  const int lane = tid & 63, w = tid >> 6;
  const int* m = mask + b * 4096;
  int v[4], s = 0;
#pragma unroll
  for (int j = 0; j < 4; ++j) { v[j] = (m[tid * 4 + j] == 0) ? 1 : 0; s += v[j]; }
  int sc = s;
  for (int d = 1; d < 64; d <<= 1) { int t = __shfl_up(sc, d); if (lane >= d) sc += t; }
  if (lane == 63) ws[w] = sc;
  __syncthreads();
  if (tid == 0) {
    int acc = 0;
    for (int i = 0; i < 16; ++i) { int t = ws[i]; ws[i] = acc; acc += t; }
    cnt[b] = acc;
  }
  __syncthreads();
  int pos = ws[w] + sc - s;
  int* p = perm + b * 4096;
#pragma unroll
  for (int j = 0; j < 4; ++j) { p[tid * 4 + j] = v[j] ? pos : -1; pos += v[j]; }
}

// ---------------- fused QKV GEMM, 128x128 tile (m97 structure) ----------------
// A = x_bf16 [8192][512]; W = wt (Q|K|V stacked, n-major [1536][512]). grid (64, 12).
// Epilogue scatters into fragment-packed Q'/K'/V' workspaces (see k_attn).
__global__ __launch_bounds__(256, 2) void k_gemmqkv(
    const short* __restrict__ A, const short* __restrict__ W,
    const float* __restrict__ bq, const float* __restrict__ bk,
    const float* __restrict__ bv, const int* __restrict__ perm,
    short* __restrict__ oq, short* __restrict__ ok, short* __restrict__ ov) {
  __shared__ short Asm[2][128 * 64];
  __shared__ short Bsm[2][128 * 64];
  const int tid = threadIdx.x;
  const int wave = tid >> 6, lane = tid & 63;
  const int lane15 = lane & 15, g = lane >> 4;
  const int wm = wave >> 1, wn = wave & 1;
  const int m0 = blockIdx.x * 128;
  const int n0 = blockIdx.y * 128;

  const char* Ag = (const char*)A + (size_t)m0 * 1024;
  const char* Bg = (const char*)W + (size_t)n0 * 1024;

  f32x4 acc[4][4] = {};

  auto stage = [&](int buf, int kt) {
    const int k0b = kt * 128;
#pragma unroll
    for (int q = 0; q < 4; ++q) {
      int s_ = (wave * 4 + q) * 64 + lane;
      int row = s_ >> 3, ch = s_ & 7;
      gload_lds16(Ag + (size_t)row * 1024 + k0b + (((ch ^ row) & 7) << 4),
                  (char*)&Asm[buf][0] + s_ * 16);
      gload_lds16(Bg + (size_t)row * 1024 + k0b + (((ch ^ row) & 7) << 4),
                  (char*)&Bsm[buf][0] + s_ * 16);
    }
  };

  stage(0, 0);
  asm volatile("s_waitcnt vmcnt(0)" ::: "memory");
  __syncthreads();

  for (int kt = 0; kt < 8; ++kt) {
    const int cur = kt & 1;
    if (kt < 7) stage(cur ^ 1, kt + 1);
#pragma unroll
    for (int kk = 0; kk < 2; ++kk) {
      bf16x8 af[4], bfr[4];
#pragma unroll
      for (int m = 0; m < 4; ++m)
        af[m] = lds_read_swz(&Asm[cur][0], wm * 64 + m * 16 + lane15, kk * 4 + g);
#pragma unroll
      for (int n = 0; n < 4; ++n)
        bfr[n] = lds_read_swz(&Bsm[cur][0], wn * 64 + n * 16 + lane15, kk * 4 + g);
      __builtin_amdgcn_s_setprio(1);
#pragma unroll
      for (int m = 0; m < 4; ++m)
#pragma unroll
        for (int n = 0; n < 4; ++n)
          acc[m][n] = MFMA16(af[m], bfr[n], acc[m][n]);
      __builtin_amdgcn_s_setprio(0);
    }
    asm volatile("s_waitcnt vmcnt(0)" ::: "memory");
    __syncthreads();
  }

#pragma unroll
  for (int nf = 0; nf < 4; ++nf) {
    const int col = n0 + wn * 64 + nf * 16 + lane15;
    const int mat = col >> 9, nn = col & 511;
    const int hh = nn >> 6, d = nn & 63;
    const float bias = ((mat == 0) ? bq : (mat == 1) ? bk : bv)[nn];
    const int dk = d >> 4, hb = (d >> 3) & 1, jj = d & 7;
#pragma unroll
    for (int mf = 0; mf < 4; ++mf) {
#pragma unroll
      for (int j = 0; j < 4; ++j) {
        const int rowg = m0 + wm * 64 + mf * 16 + g * 4 + j;
        const int b_ = rowg >> 12, sl = rowg & 4095;
        const size_t bh = (size_t)(b_ * 8 + hh);
        const float v = acc[mf][nf][j] + bias;
        if (mat == 0) {
          oq[bh * 262144 +
             (size_t)(((sl >> 5) * 4 + dk) * 64 + hb * 32 + (sl & 31)) * 8 + jj] =
              f2b(v * QSCALE);
        } else {
          const int pm_ = perm[b_ * 4096 + sl];
          if (pm_ >= 0) {
            const int t = pm_ >> 6, r = pm_ & 63;
            if (mat == 1) {
              ok[bh * 262144 +
                 (size_t)((t * 8 + dk * 2 + (r >> 5)) * 64 + hb * 32 + (r & 31)) * 8 + jj] =
                  f2b(v);
            } else {
              const int mm = (r & ~12) | (((r >> 2) & 1) << 3) | (((r >> 3) & 1) << 2);
              ov[bh * 262144 +
                 (size_t)((t * 8 + ((mm >> 4) & 3) * 2 + (d >> 5)) * 64 +
                          ((mm >> 3) & 1) * 32 + (d & 31)) * 8 + (mm & 7)] = f2b(v);
            }
          }
        }
      }
    }
  }
}

// ---------------- output projection GEMM, 128x64 tile, grid (64, 8) ----------------
__global__ __launch_bounds__(256, 2) void k_gemmo(
    const short* __restrict__ A, const short* __restrict__ W,
    const float* __restrict__ bias, float* __restrict__ fo) {
  __shared__ short Asm[2][128 * 64];
  __shared__ short Bsm[2][64 * 64];
  const int tid = threadIdx.x;
  const int wave = tid >> 6, lane = tid & 63;
  const int lane15 = lane & 15, g = lane >> 4;
  const int wm = wave >> 1, wn = wave & 1;
  const int m0 = blockIdx.x * 128;
  const int n0 = blockIdx.y * 64;

  const char* Ag = (const char*)A + (size_t)m0 * 1024;
  const char* Bg = (const char*)W + (size_t)n0 * 1024;

  f32x4 acc[4][2] = {};

  auto stage = [&](int buf, int kt) {
    const int k0b = kt * 128;
#pragma unroll
    for (int q = 0; q < 4; ++q) {
      int s_ = (wave * 4 + q) * 64 + lane;
      int row = s_ >> 3, ch = s_ & 7;
      gload_lds16(Ag + (size_t)row * 1024 + k0b + (((ch ^ row) & 7) << 4),
                  (char*)&Asm[buf][0] + s_ * 16);
    }
#pragma unroll
    for (int q = 0; q < 2; ++q) {
      int s_ = (wave * 2 + q) * 64 + lane;
      int row = s_ >> 3, ch = s_ & 7;
      gload_lds16(Bg + (size_t)row * 1024 + k0b + (((ch ^ row) & 7) << 4),
                  (char*)&Bsm[buf][0] + s_ * 16);
    }
  };

  stage(0, 0);
  asm volatile("s_waitcnt vmcnt(0)" ::: "memory");
  __syncthreads();

  for (int kt = 0; kt < 8; ++kt) {
    const int cur = kt & 1;
    if (kt < 7) stage(cur ^ 1, kt + 1);
#pragma unroll
    for (int kk = 0; kk < 2; ++kk) {
      bf16x8 af[4], bfr[2];
#pragma unroll
      for (int m = 0; m < 4; ++m)
        af[m] = lds_read_swz(&Asm[cur][0], wm * 64 + m * 16 + lane15, kk * 4 + g);
#pragma unroll
      for (int n = 0; n < 2; ++n)
        bfr[n] = lds_read_swz(&Bsm[cur][0], wn * 32 + n * 16 + lane15, kk * 4 + g);
      __builtin_amdgcn_s_setprio(1);
#pragma unroll
      for (int m = 0; m < 4; ++m)
#pragma unroll
        for (int n = 0; n < 2; ++n)
          acc[m][n] = MFMA16(af[m], bfr[n], acc[m][n]);
      __builtin_amdgcn_s_setprio(0);
    }
    asm volatile("s_waitcnt vmcnt(0)" ::: "memory");
    __syncthreads();
  }

#pragma unroll
  for (int nf = 0; nf < 2; ++nf) {
    const int col = n0 + wn * 32 + nf * 16 + lane15;
    const float b = bias[col];
#pragma unroll
    for (int mf = 0; mf < 4; ++mf)
#pragma unroll
      for (int j = 0; j < 4; ++j) {
        const int rowg = m0 + wm * 64 + mf * 16 + g * 4 + j;
        fo[(size_t)rowg * 512 + col] = acc[mf][nf][j] + b;
      }
  }
}

// ---------------- flash attention: LDS-staged K/V, fixed-base softmax ----------------
// grid 512 (XCD-swizzled -> (qt, bh)); 4 waves x 32 q-rows; 64-key tiles, double-buffered.
// K/V staged once per block via global_load_lds (linear fragment order, dest =
// uniform base + lane*16); compute reads are full-width conflict-free ds_read_b128.
// QK^T = mfma(K,Q): score col = q = lane&31; p = exp2(s) (scores C-S-bounded, shift
// cancels in o/l). PV = mfma(V',P); V' key order bit-swapped so P is lane-local.
__global__ __launch_bounds__(256, 2) void k_attn(
    const short* __restrict__ Qp, const short* __restrict__ Kp,
    const short* __restrict__ Vp, const int* __restrict__ cnt,
    short* __restrict__ out) {
  __shared__ short Ks[2][8][512];  // [buf][fragment][lane*8]
  __shared__ short Vs[2][8][512];

  const int tid = threadIdx.x;
  const int wave = tid >> 6, lane = tid & 63;
  const int l31 = lane & 31, h = lane >> 5;
  // XCD-bijective swizzle: 512 blocks = 8 XCDs x 64 -> each XCD sees 2 heads only
  const int bid = blockIdx.x;
  const int sid = (bid & 7) * 64 + (bid >> 3);
  const int qt = sid & 31, bh = sid >> 5;
  const int b = bh >> 3, hh = bh & 7;
  const int qb = qt * 4 + wave;  // 32-row q-block index

  const short* Qg = Qp + (size_t)bh * 262144;
  const short* Kg = Kp + (size_t)bh * 262144;
  const short* Vg = Vp + (size_t)bh * 262144;

  bf16x8 qreg[4];
#pragma unroll
  for (int dk = 0; dk < 4; ++dk)
    qreg[dk] = *(const bf16x8*)(Qg + ((size_t)(qb * 4 + dk) * 64 + lane) * 8);

  const int cn = cnt[b];
  const int nt = max(1, (cn + 63) >> 6);
  const int lim = cn - (nt - 1) * 64;  // keys in last tile (0..64)

  auto stage = [&](int buf, int t) {
#pragma unroll
    for (int q = 0; q < 2; ++q) {
      const int u = wave * 2 + q;  // each wave stages 2 K + 2 V fragments
      gload_lds16(Kg + ((size_t)(t * 8 + u) * 64 + lane) * 8, &Ks[buf][u][lane * 8]);
      gload_lds16(Vg + ((size_t)(t * 8 + u) * 64 + lane) * 8, &Vs[buf][u][lane * 8]);
    }
  };
  auto ldsK = [&](int buf, int u) { return *(const bf16x8*)&Ks[buf][u][lane * 8]; };
  auto ldsV = [&](int buf, int u) { return *(const bf16x8*)&Vs[buf][u][lane * 8]; };

  f32x16 o0 = {}, o1 = {};
  float l_ = 0.f;

  stage(0, 0);
  __syncthreads();

  for (int t = 0; t < nt; ++t) {
    const int cur = t & 1;
    if (t + 1 < nt) stage(cur ^ 1, t + 1);  // issue early, drained by end barrier

    f32x16 s0v = {}, s1v = {};
    __builtin_amdgcn_s_setprio(1);
#pragma unroll
    for (int dk = 0; dk < 4; ++dk) {
      s0v = MFMA32(ldsK(cur, 2 * dk), qreg[dk], s0v);
      s1v = MFMA32(ldsK(cur, 2 * dk + 1), qreg[dk], s1v);
    }
    __builtin_amdgcn_s_setprio(0);

    if (t == nt - 1 && lim < 64) {
#pragma unroll
      for (int i = 0; i < 16; ++i) {
        const int r0 = (i & 3) + 8 * (i >> 2) + 4 * h;
        if (r0 >= lim) s0v[i] = -1e30f;
        if (r0 + 32 >= lim) s1v[i] = -1e30f;
      }
    }

    unsigned int wA[8], wB[8];
    float ts = 0.f;
#pragma unroll
    for (int j2 = 0; j2 < 8; ++j2) {
      float a0 = exp2fast(s0v[2 * j2]);
      float a1 = exp2fast(s0v[2 * j2 + 1]);
      float b0 = exp2fast(s1v[2 * j2]);
      float b1 = exp2fast(s1v[2 * j2 + 1]);
      ts += (a0 + a1) + (b0 + b1);
      asm("v_cvt_pk_bf16_f32 %0, %1, %2" : "=v"(wA[j2]) : "v"(a0), "v"(a1));
      asm("v_cvt_pk_bf16_f32 %0, %1, %2" : "=v"(wB[j2]) : "v"(b0), "v"(b1));
    }
    l_ += ts;

    __builtin_amdgcn_s_setprio(1);
#pragma unroll
    for (int s = 0; s < 4; ++s) {
      const bf16x8 v0 = ldsV(cur, 2 * s);
      const bf16x8 v1 = ldsV(cur, 2 * s + 1);
      const unsigned int* w = (s < 2) ? wA : wB;
      union PU { u32x4 u; bf16x8 f; } pu;
      pu.u[0] = w[4 * (s & 1) + 0];
      pu.u[1] = w[4 * (s & 1) + 1];
      pu.u[2] = w[4 * (s & 1) + 2];
      pu.u[3] = w[4 * (s & 1) + 3];
      o0 = MFMA32(v0, pu.f, o0);
      o1 = MFMA32(v1, pu.f, o1);
    }
    __builtin_amdgcn_s_setprio(0);

    __syncthreads();  // drains staging loads (vmcnt 0) + releases buf for overwrite
  }

  l_ += __shfl_xor(l_, 32);
  const float inv = 1.0f / l_;
  short* og = out + (size_t)(b * 4096 + qb * 32 + l31) * 512 + hh * 64;
#pragma unroll
  for (int r2 = 0; r2 < 4; ++r2) {
    {
      const int base = 8 * r2 + 4 * h;
      short4 s4;
      s4.x = f2b(o0[4 * r2 + 0] * inv);
      s4.y = f2b(o0[4 * r2 + 1] * inv);
      s4.z = f2b(o0[4 * r2 + 2] * inv);
      s4.w = f2b(o0[4 * r2 + 3] * inv);
      *(short4*)(og + base) = s4;
    }
    {
      const int base = 32 + 8 * r2 + 4 * h;
      short4 s4;
      s4.x = f2b(o1[4 * r2 + 0] * inv);
      s4.y = f2b(o1[4 * r2 + 1] * inv);
      s4.z = f2b(o1[4 * r2 + 2] * inv);
      s4.w = f2b(o1[4 * r2 + 3] * inv);
      *(short4*)(og + base) = s4;
    }
  }
}

// ---------------- launch ----------------
extern "C" void kernel_launch(void* const* d_in, const int* in_sizes, int n_in,
                              void* d_out, int out_size, void* d_ws, size_t ws_size,
                              hipStream_t stream) {
  const float* x  = (const float*)d_in[0];
  const int* mask = (const int*)d_in[1];
  const float* Wq = (const float*)d_in[2];
  const float* bq = (const float*)d_in[3];
  const float* Wk = (const float*)d_in[4];
  const float* bk = (const float*)d_in[5];
  const float* Wv = (const float*)d_in[6];
  const float* bv = (const float*)d_in[7];
  const float* Wo = (const float*)d_in[8];
  const float* bo = (const float*)d_in[9];
  float* out = (float*)d_out;

  short* xb   = (short*)d_ws;                        // 8192*512 bf16
  short* wt   = xb + (size_t)8192 * 512;             // 4*512*512 bf16
  short* qws  = wt + (size_t)4 * 512 * 512;          // Q' fragment-packed, QSCALE'd
  short* kws  = qws + (size_t)8192 * 512;            // K' fragment-packed, compacted
  short* vws  = kws + (size_t)8192 * 512;            // V' fragment-packed, compacted+bitswap
  short* aout = vws + (size_t)8192 * 512;            // [b*s][512] bf16
  int* perm   = (int*)(aout + (size_t)8192 * 512);   // [b][s]
  int* cntw   = perm + 8192;

  k_cvt_x<<<4096, 256, 0, stream>>>(x, xb);
  k_cvt_w<<<4096, 256, 0, stream>>>(Wq, Wk, Wv, Wo, wt);
  k_scan<<<2, 1024, 0, stream>>>(mask, perm, cntw);
  k_gemmqkv<<<dim3(64, 12), 256, 0, stream>>>(xb, wt, bq, bk, bv, perm, qws, kws, vws);
  k_attn<<<512, 256, 0, stream>>>(qws, kws, vws, cntw, aout);
  k_gemmo<<<dim3(64, 8), 256, 0, stream>>>(aout, wt + (size_t)3 * 512 * 512, bo, out);
}

// Round 8
// 166.941 us; speedup vs baseline: 1.2554x; 1.0809x over previous
//
#include <hip/hip_runtime.h>
#include <hip/hip_bf16.h>
#include <stdint.h>

typedef __attribute__((ext_vector_type(8))) short bf16x8;
typedef __attribute__((ext_vector_type(4))) float f32x4;
typedef __attribute__((ext_vector_type(16))) float f32x16;
typedef __attribute__((ext_vector_type(4))) unsigned int u32x4;

#define MFMA16(a, b, c) __builtin_amdgcn_mfma_f32_16x16x32_bf16(a, b, c, 0, 0, 0)
#define MFMA32(a, b, c) __builtin_amdgcn_mfma_f32_32x32x16_bf16(a, b, c, 0, 0, 0)

constexpr float QSCALE = 0.04419417382415922f * 1.4426950408889634f;  // 1/sqrt(512) * log2(e)

__device__ __forceinline__ void gload_lds16(const void* g, void* l) {
  __builtin_amdgcn_global_load_lds((const __attribute__((address_space(1))) uint32_t*)g,
                                   (__attribute__((address_space(3))) uint32_t*)l, 16, 0, 0);
}
__device__ __forceinline__ bf16x8 lds_read_swz(const short* base, int row, int ch) {
  return *(const bf16x8*)((const char*)base + row * 128 + (((ch ^ row) & 7) << 4));
}
__device__ __forceinline__ short f2b(float f) {
  __hip_bfloat16 h = __float2bfloat16(f);
  return *reinterpret_cast<short*>(&h);
}
__device__ __forceinline__ float exp2fast(float x) {
#if __has_builtin(__builtin_amdgcn_exp2f)
  return __builtin_amdgcn_exp2f(x);
#else
  return exp2f(x);
#endif
}

// ---------------- converters ----------------
__global__ void k_cvt_x(const float* __restrict__ x, short* __restrict__ xb) {
  const int i = blockIdx.x * 256 + threadIdx.x;
  const float4 v = ((const float4*)x)[i];
  short4 o;
  o.x = f2b(v.x); o.y = f2b(v.y); o.z = f2b(v.z); o.w = f2b(v.w);
  ((short4*)xb)[i] = o;
}

// wt[mat][n][k] = bf16(W_mat[k][n]) via LDS-tiled 64x64 transpose (coalesced both sides)
__global__ void k_cvt_w(const float* __restrict__ wq, const float* __restrict__ wk,
                        const float* __restrict__ wv, const float* __restrict__ wo,
                        short* __restrict__ wt) {
  __shared__ float tile[64][65];
  const int mat = blockIdx.x >> 6;      // 4 mats x 64 tiles
  const int t6 = blockIdx.x & 63;
  const int k0 = (t6 >> 3) * 64, n0 = (t6 & 7) * 64;
  const float* w = (mat == 0) ? wq : (mat == 1) ? wk : (mat == 2) ? wv : wo;
  const int c = threadIdx.x & 63, r4 = threadIdx.x >> 6;  // 256 thr: 4 rows/pass
#pragma unroll
  for (int p = 0; p < 16; ++p) {
    const int r = p * 4 + r4;
    tile[r][c] = w[(k0 + r) * 512 + n0 + c];   // coalesced read along n
  }
  __syncthreads();
#pragma unroll
  for (int p = 0; p < 16; ++p) {
    const int r = p * 4 + r4;                   // n-row of wt
    wt[mat * 262144 + (n0 + r) * 512 + k0 + c] = f2b(tile[c][r]);  // coalesced along k
  }
}

// ---------------- prefix-scan of kept keys (mask==0) ----------------
__global__ void k_scan(const int* __restrict__ mask, int* __restrict__ perm,
                       int* __restrict__ cnt) {
  __shared__ int ws[16];
  const int b = blockIdx.x, tid = threadIdx.x;  // 1024 threads
  const int lane = tid & 63, w = tid >> 6;
  const int* m = mask + b * 4096;
  int v[4], s = 0;
#pragma unroll
  for (int j = 0; j < 4; ++j) { v[j] = (m[tid * 4 + j] == 0) ? 1 : 0; s += v[j]; }
  int sc = s;
  for (int d = 1; d < 64; d <<= 1) { int t = __shfl_up(sc, d); if (lane >= d) sc += t; }
  if (lane == 63) ws[w] = sc;
  __syncthreads();
  if (tid == 0) {
    int acc = 0;
    for (int i = 0; i < 16; ++i) { int t = ws[i]; ws[i] = acc; acc += t; }
    cnt[b] = acc;
  }
  __syncthreads();
  int pos = ws[w] + sc - s;
  int* p = perm + b * 4096;
#pragma unroll
  for (int j = 0; j < 4; ++j) { p[tid * 4 + j] = v[j] ? pos : -1; pos += v[j]; }
}

// ---------------- fused QKV GEMM, 128x128 tile, swapped-operand epilogue ----------------
// A = x_bf16 [8192][512]; W = wt (Q|K|V stacked n-major [1536][512]). grid (64, 12).
// MFMA called as mfma(bfr, af): per-thread fragment = C[row=lane15][col=g*4+j] ->
// j spans 4 consecutive output cols (d) => vectorized short4 scatter into Q'/K'/V'.
// mat = blockIdx.y>>2 is block-uniform; perm lookup once per mf.
__global__ __launch_bounds__(256, 2) void k_gemmqkv(
    const short* __restrict__ A, const short* __restrict__ W,
    const float* __restrict__ bq, const float* __restrict__ bk,
    const float* __restrict__ bv, const int* __restrict__ perm,
    short* __restrict__ oq, short* __restrict__ ok, short* __restrict__ ov) {
  __shared__ short Asm[2][128 * 64];
  __shared__ short Bsm[2][128 * 64];
  const int tid = threadIdx.x;
  const int wave = tid >> 6, lane = tid & 63;
  const int lane15 = lane & 15, g = lane >> 4;
  const int wm = wave >> 1, wn = wave & 1;
  const int m0 = blockIdx.x * 128;
  const int n0 = blockIdx.y * 128;

  const char* Ag = (const char*)A + (size_t)m0 * 1024;
  const char* Bg = (const char*)W + (size_t)n0 * 1024;

  f32x4 acc[4][4] = {};

  auto stage = [&](int buf, int kt) {
    const int k0b = kt * 128;
#pragma unroll
    for (int q = 0; q < 4; ++q) {
      int s_ = (wave * 4 + q) * 64 + lane;
      int row = s_ >> 3, ch = s_ & 7;
      gload_lds16(Ag + (size_t)row * 1024 + k0b + (((ch ^ row) & 7) << 4),
                  (char*)&Asm[buf][0] + s_ * 16);
      gload_lds16(Bg + (size_t)row * 1024 + k0b + (((ch ^ row) & 7) << 4),
                  (char*)&Bsm[buf][0] + s_ * 16);
    }
  };

  stage(0, 0);
  asm volatile("s_waitcnt vmcnt(0)" ::: "memory");
  __syncthreads();

  for (int kt = 0; kt < 8; ++kt) {
    const int cur = kt & 1;
    if (kt < 7) stage(cur ^ 1, kt + 1);
#pragma unroll
    for (int kk = 0; kk < 2; ++kk) {
      bf16x8 af[4], bfr[4];
#pragma unroll
      for (int m = 0; m < 4; ++m)
        af[m] = lds_read_swz(&Asm[cur][0], wm * 64 + m * 16 + lane15, kk * 4 + g);
#pragma unroll
      for (int n = 0; n < 4; ++n)
        bfr[n] = lds_read_swz(&Bsm[cur][0], wn * 64 + n * 16 + lane15, kk * 4 + g);
      __builtin_amdgcn_s_setprio(1);
#pragma unroll
      for (int m = 0; m < 4; ++m)
#pragma unroll
        for (int n = 0; n < 4; ++n)
          acc[m][n] = MFMA16(bfr[n], af[m], acc[m][n]);  // swapped: C^T fragment
      __builtin_amdgcn_s_setprio(0);
    }
    asm volatile("s_waitcnt vmcnt(0)" ::: "memory");
    __syncthreads();
  }

  const int mat = blockIdx.y >> 2;                 // block-uniform
  const float* bptr = (mat == 0) ? bq : (mat == 1) ? bk : bv;
  const int hh = ((n0 & 511) >> 6) + wn;           // head
  const int hb = g >> 1, j4 = (g & 1) * 4;

#pragma unroll
  for (int mf = 0; mf < 4; ++mf) {
    const int rowg = m0 + wm * 64 + mf * 16 + lane15;  // sequence row
    const int b_ = rowg >> 12, sl = rowg & 4095;
    const size_t bh = (size_t)(b_ * 8 + hh);
    int pm_ = 0;
    if (mat != 0) pm_ = perm[b_ * 4096 + sl];
#pragma unroll
    for (int nf = 0; nf < 4; ++nf) {
      const int nn = (n0 & 511) + wn * 64 + nf * 16 + g * 4;
      const float4 b4 = *(const float4*)(bptr + nn);
      const float v0 = acc[mf][nf][0] + b4.x;
      const float v1 = acc[mf][nf][1] + b4.y;
      const float v2 = acc[mf][nf][2] + b4.z;
      const float v3 = acc[mf][nf][3] + b4.w;
      if (mat == 0) {
        short4 s4;
        s4.x = f2b(v0 * QSCALE); s4.y = f2b(v1 * QSCALE);
        s4.z = f2b(v2 * QSCALE); s4.w = f2b(v3 * QSCALE);
        *(short4*)(oq + bh * 262144 +
                   (size_t)(((sl >> 5) * 4 + nf) * 64 + hb * 32 + (sl & 31)) * 8 + j4) = s4;
      } else if (pm_ >= 0) {
        const int t = pm_ >> 6, r = pm_ & 63;
        if (mat == 1) {
          short4 s4;
          s4.x = f2b(v0); s4.y = f2b(v1); s4.z = f2b(v2); s4.w = f2b(v3);
          *(short4*)(ok + bh * 262144 +
                     (size_t)((t * 8 + nf * 2 + (r >> 5)) * 64 + hb * 32 + (r & 31)) * 8 + j4) = s4;
        } else {
          const int mm = (r & ~12) | (((r >> 2) & 1) << 3) | (((r >> 3) & 1) << 2);
          short* base = ov + bh * 262144 +
                        (size_t)((t * 8 + ((mm >> 4) & 3) * 2 + (nf >> 1)) * 64 +
                                 ((mm >> 3) & 1) * 32 + (nf & 1) * 16 + g * 4) * 8 + (mm & 7);
          base[0] = f2b(v0); base[8] = f2b(v1); base[16] = f2b(v2); base[24] = f2b(v3);
        }
      }
    }
  }
}

// ---------------- output projection GEMM, 128x64 tile, grid (64, 8) ----------------
// Swapped-operand epilogue: float4 stores.
__global__ __launch_bounds__(256, 2) void k_gemmo(
    const short* __restrict__ A, const short* __restrict__ W,
    const float* __restrict__ bias, float* __restrict__ fo) {
  __shared__ short Asm[2][128 * 64];
  __shared__ short Bsm[2][64 * 64];
  const int tid = threadIdx.x;
  const int wave = tid >> 6, lane = tid & 63;
  const int lane15 = lane & 15, g = lane >> 4;
  const int wm = wave >> 1, wn = wave & 1;
  const int m0 = blockIdx.x * 128;
  const int n0 = blockIdx.y * 64;

  const char* Ag = (const char*)A + (size_t)m0 * 1024;
  const char* Bg = (const char*)W + (size_t)n0 * 1024;

  f32x4 acc[4][2] = {};

  auto stage = [&](int buf, int kt) {
    const int k0b = kt * 128;
#pragma unroll
    for (int q = 0; q < 4; ++q) {
      int s_ = (wave * 4 + q) * 64 + lane;
      int row = s_ >> 3, ch = s_ & 7;
      gload_lds16(Ag + (size_t)row * 1024 + k0b + (((ch ^ row) & 7) << 4),
                  (char*)&Asm[buf][0] + s_ * 16);
    }
#pragma unroll
    for (int q = 0; q < 2; ++q) {
      int s_ = (wave * 2 + q) * 64 + lane;
      int row = s_ >> 3, ch = s_ & 7;
      gload_lds16(Bg + (size_t)row * 1024 + k0b + (((ch ^ row) & 7) << 4),
                  (char*)&Bsm[buf][0] + s_ * 16);
    }
  };

  stage(0, 0);
  asm volatile("s_waitcnt vmcnt(0)" ::: "memory");
  __syncthreads();

  for (int kt = 0; kt < 8; ++kt) {
    const int cur = kt & 1;
    if (kt < 7) stage(cur ^ 1, kt + 1);
#pragma unroll
    for (int kk = 0; kk < 2; ++kk) {
      bf16x8 af[4], bfr[2];
#pragma unroll
      for (int m = 0; m < 4; ++m)
        af[m] = lds_read_swz(&Asm[cur][0], wm * 64 + m * 16 + lane15, kk * 4 + g);
#pragma unroll
      for (int n = 0; n < 2; ++n)
        bfr[n] = lds_read_swz(&Bsm[cur][0], wn * 32 + n * 16 + lane15, kk * 4 + g);
      __builtin_amdgcn_s_setprio(1);
#pragma unroll
      for (int m = 0; m < 4; ++m)
#pragma unroll
        for (int n = 0; n < 2; ++n)
          acc[m][n] = MFMA16(bfr[n], af[m], acc[m][n]);  // swapped
      __builtin_amdgcn_s_setprio(0);
    }
    asm volatile("s_waitcnt vmcnt(0)" ::: "memory");
    __syncthreads();
  }

#pragma unroll
  for (int mf = 0; mf < 4; ++mf) {
    const int rowg = m0 + wm * 64 + mf * 16 + lane15;
#pragma unroll
    for (int nf = 0; nf < 2; ++nf) {
      const int cb = n0 + wn * 32 + nf * 16 + g * 4;
      const float4 b4 = *(const float4*)(bias + cb);
      float4 o4;
      o4.x = acc[mf][nf][0] + b4.x;
      o4.y = acc[mf][nf][1] + b4.y;
      o4.z = acc[mf][nf][2] + b4.z;
      o4.w = acc[mf][nf][3] + b4.w;
      *(float4*)(fo + (size_t)rowg * 512 + cb) = o4;
    }
  }
}

// ---------------- flash attention: LDS-staged K/V, fixed-base softmax ----------------
// (unchanged from round 7 — validated at 52 us, FETCH 8.2 MB, 0 bank conflicts)
__global__ __launch_bounds__(256, 2) void k_attn(
    const short* __restrict__ Qp, const short* __restrict__ Kp,
    const short* __restrict__ Vp, const int* __restrict__ cnt,
    short* __restrict__ out) {
  __shared__ short Ks[2][8][512];  // [buf][fragment][lane*8]
  __shared__ short Vs[2][8][512];

  const int tid = threadIdx.x;
  const int wave = tid >> 6, lane = tid & 63;
  const int l31 = lane & 31, h = lane >> 5;
  const int bid = blockIdx.x;
  const int sid = (bid & 7) * 64 + (bid >> 3);
  const int qt = sid & 31, bh = sid >> 5;
  const int b = bh >> 3, hh = bh & 7;
  const int qb = qt * 4 + wave;  // 32-row q-block index

  const short* Qg = Qp + (size_t)bh * 262144;
  const short* Kg = Kp + (size_t)bh * 262144;
  const short* Vg = Vp + (size_t)bh * 262144;

  bf16x8 qreg[4];
#pragma unroll
  for (int dk = 0; dk < 4; ++dk)
    qreg[dk] = *(const bf16x8*)(Qg + ((size_t)(qb * 4 + dk) * 64 + lane) * 8);

  const int cn = cnt[b];
  const int nt = max(1, (cn + 63) >> 6);
  const int lim = cn - (nt - 1) * 64;  // keys in last tile (0..64)

  auto stage = [&](int buf, int t) {
#pragma unroll
    for (int q = 0; q < 2; ++q) {
      const int u = wave * 2 + q;
      gload_lds16(Kg + ((size_t)(t * 8 + u) * 64 + lane) * 8, &Ks[buf][u][lane * 8]);
      gload_lds16(Vg + ((size_t)(t * 8 + u) * 64 + lane) * 8, &Vs[buf][u][lane * 8]);
    }
  };
  auto ldsK = [&](int buf, int u) { return *(const bf16x8*)&Ks[buf][u][lane * 8]; };
  auto ldsV = [&](int buf, int u) { return *(const bf16x8*)&Vs[buf][u][lane * 8]; };

  f32x16 o0 = {}, o1 = {};
  float l_ = 0.f;

  stage(0, 0);
  __syncthreads();

  for (int t = 0; t < nt; ++t) {
    const int cur = t & 1;
    if (t + 1 < nt) stage(cur ^ 1, t + 1);

    f32x16 s0v = {}, s1v = {};
    __builtin_amdgcn_s_setprio(1);
#pragma unroll
    for (int dk = 0; dk < 4; ++dk) {
      s0v = MFMA32(ldsK(cur, 2 * dk), qreg[dk], s0v);
      s1v = MFMA32(ldsK(cur, 2 * dk + 1), qreg[dk], s1v);
    }
    __builtin_amdgcn_s_setprio(0);

    if (t == nt - 1 && lim < 64) {
#pragma unroll
      for (int i = 0; i < 16; ++i) {
        const int r0 = (i & 3) + 8 * (i >> 2) + 4 * h;
        if (r0 >= lim) s0v[i] = -1e30f;
        if (r0 + 32 >= lim) s1v[i] = -1e30f;
      }
    }

    unsigned int wA[8], wB[8];
    float ts = 0.f;
#pragma unroll
    for (int j2 = 0; j2 < 8; ++j2) {
      float a0 = exp2fast(s0v[2 * j2]);
      float a1 = exp2fast(s0v[2 * j2 + 1]);
      float b0 = exp2fast(s1v[2 * j2]);
      float b1 = exp2fast(s1v[2 * j2 + 1]);
      ts += (a0 + a1) + (b0 + b1);
      asm("v_cvt_pk_bf16_f32 %0, %1, %2" : "=v"(wA[j2]) : "v"(a0), "v"(a1));
      asm("v_cvt_pk_bf16_f32 %0, %1, %2" : "=v"(wB[j2]) : "v"(b0), "v"(b1));
    }
    l_ += ts;

    __builtin_amdgcn_s_setprio(1);
#pragma unroll
    for (int s = 0; s < 4; ++s) {
      const bf16x8 v0 = ldsV(cur, 2 * s);
      const bf16x8 v1 = ldsV(cur, 2 * s + 1);
      const unsigned int* w = (s < 2) ? wA : wB;
      union PU { u32x4 u; bf16x8 f; } pu;
      pu.u[0] = w[4 * (s & 1) + 0];
      pu.u[1] = w[4 * (s & 1) + 1];
      pu.u[2] = w[4 * (s & 1) + 2];
      pu.u[3] = w[4 * (s & 1) + 3];
      o0 = MFMA32(v0, pu.f, o0);
      o1 = MFMA32(v1, pu.f, o1);
    }
    __builtin_amdgcn_s_setprio(0);

    __syncthreads();
  }

  l_ += __shfl_xor(l_, 32);
  const float inv = 1.0f / l_;
  short* og = out + (size_t)(b * 4096 + qb * 32 + l31) * 512 + hh * 64;
#pragma unroll
  for (int r2 = 0; r2 < 4; ++r2) {
    {
      const int base = 8 * r2 + 4 * h;
      short4 s4;
      s4.x = f2b(o0[4 * r2 + 0] * inv);
      s4.y = f2b(o0[4 * r2 + 1] * inv);
      s4.z = f2b(o0[4 * r2 + 2] * inv);
      s4.w = f2b(o0[4 * r2 + 3] * inv);
      *(short4*)(og + base) = s4;
    }
    {
      const int base = 32 + 8 * r2 + 4 * h;
      short4 s4;
      s4.x = f2b(o1[4 * r2 + 0] * inv);
      s4.y = f2b(o1[4 * r2 + 1] * inv);
      s4.z = f2b(o1[4 * r2 + 2] * inv);
      s4.w = f2b(o1[4 * r2 + 3] * inv);
      *(short4*)(og + base) = s4;
    }
  }
}

// ---------------- launch ----------------
extern "C" void kernel_launch(void* const* d_in, const int* in_sizes, int n_in,
                              void* d_out, int out_size, void* d_ws, size_t ws_size,
                              hipStream_t stream) {
  const float* x  = (const float*)d_in[0];
  const int* mask = (const int*)d_in[1];
  const float* Wq = (const float*)d_in[2];
  const float* bq = (const float*)d_in[3];
  const float* Wk = (const float*)d_in[4];
  const float* bk = (const float*)d_in[5];
  const float* Wv = (const float*)d_in[6];
  const float* bv = (const float*)d_in[7];
  const float* Wo = (const float*)d_in[8];
  const float* bo = (const float*)d_in[9];
  float* out = (float*)d_out;

  short* xb   = (short*)d_ws;                        // 8192*512 bf16
  short* wt   = xb + (size_t)8192 * 512;             // 4*512*512 bf16
  short* qws  = wt + (size_t)4 * 512 * 512;          // Q' fragment-packed, QSCALE'd
  short* kws  = qws + (size_t)8192 * 512;            // K' fragment-packed, compacted
  short* vws  = kws + (size_t)8192 * 512;            // V' fragment-packed, compacted+bitswap
  short* aout = vws + (size_t)8192 * 512;            // [b*s][512] bf16
  int* perm   = (int*)(aout + (size_t)8192 * 512);   // [b][s]
  int* cntw   = perm + 8192;

  k_cvt_x<<<4096, 256, 0, stream>>>(x, xb);
  k_cvt_w<<<256, 256, 0, stream>>>(Wq, Wk, Wv, Wo, wt);
  k_scan<<<2, 1024, 0, stream>>>(mask, perm, cntw);
  k_gemmqkv<<<dim3(64, 12), 256, 0, stream>>>(xb, wt, bq, bk, bv, perm, qws, kws, vws);
  k_attn<<<512, 256, 0, stream>>>(qws, kws, vws, cntw, aout);
  k_gemmo<<<dim3(64, 8), 256, 0, stream>>>(aout, wt + (size_t)3 * 512 * 512, bo, out);
}

// Round 9
// 163.910 us; speedup vs baseline: 1.2786x; 1.0185x over previous
//
#include <hip/hip_runtime.h>
#include <hip/hip_bf16.h>
#include <stdint.h>

typedef __attribute__((ext_vector_type(8))) short bf16x8;
typedef __attribute__((ext_vector_type(4))) float f32x4;
typedef __attribute__((ext_vector_type(16))) float f32x16;
typedef __attribute__((ext_vector_type(4))) unsigned int u32x4;

#define MFMA16(a, b, c) __builtin_amdgcn_mfma_f32_16x16x32_bf16(a, b, c, 0, 0, 0)
#define MFMA32(a, b, c) __builtin_amdgcn_mfma_f32_32x32x16_bf16(a, b, c, 0, 0, 0)

constexpr float QSCALE = 0.04419417382415922f * 1.4426950408889634f;  // 1/sqrt(512) * log2(e)

__device__ __forceinline__ void gload_lds16(const void* g, void* l) {
  __builtin_amdgcn_global_load_lds((const __attribute__((address_space(1))) uint32_t*)g,
                                   (__attribute__((address_space(3))) uint32_t*)l, 16, 0, 0);
}
__device__ __forceinline__ bf16x8 lds_read_swz(const short* base, int row, int ch) {
  return *(const bf16x8*)((const char*)base + row * 128 + (((ch ^ row) & 7) << 4));
}
__device__ __forceinline__ short f2b(float f) {
  __hip_bfloat16 h = __float2bfloat16(f);
  return *reinterpret_cast<short*>(&h);
}
__device__ __forceinline__ float exp2fast(float x) {
#if __has_builtin(__builtin_amdgcn_exp2f)
  return __builtin_amdgcn_exp2f(x);
#else
  return exp2f(x);
#endif
}

// ---------------- fused preprocessing: x->bf16 | W transpose->bf16 | mask scan --------
// grid 4354: [0,4096) cvt_x ; [4096,4352) cvt_w ; [4352,4354) scan
__global__ void k_prep(const float* __restrict__ x,
                       const float* __restrict__ wq, const float* __restrict__ wk,
                       const float* __restrict__ wv, const float* __restrict__ wo,
                       const int* __restrict__ mask,
                       short* __restrict__ xb, short* __restrict__ wt,
                       int* __restrict__ perm, int* __restrict__ cnt) {
  __shared__ float tile[64][65];
  __shared__ int ws4[4];
  const int bid = blockIdx.x, tid = threadIdx.x;

  if (bid < 4096) {
    const int i = bid * 256 + tid;
    const float4 v = ((const float4*)x)[i];
    short4 o;
    o.x = f2b(v.x); o.y = f2b(v.y); o.z = f2b(v.z); o.w = f2b(v.w);
    ((short4*)xb)[i] = o;
  } else if (bid < 4352) {
    const int bp = bid - 4096;
    const int mat = bp >> 6;
    const int t6 = bp & 63;
    const int k0 = (t6 >> 3) * 64, n0 = (t6 & 7) * 64;
    const float* w = (mat == 0) ? wq : (mat == 1) ? wk : (mat == 2) ? wv : wo;
    const int c = tid & 63, r4 = tid >> 6;
#pragma unroll
    for (int p = 0; p < 16; ++p) {
      const int r = p * 4 + r4;
      tile[r][c] = w[(k0 + r) * 512 + n0 + c];
    }
    __syncthreads();
#pragma unroll
    for (int p = 0; p < 16; ++p) {
      const int r = p * 4 + r4;
      wt[mat * 262144 + (n0 + r) * 512 + k0 + c] = f2b(tile[c][r]);
    }
  } else {
    const int b = bid - 4352;
    const int lane = tid & 63, w = tid >> 6;
    const int* m = mask + b * 4096;
    int v[16], s = 0;
#pragma unroll
    for (int j = 0; j < 16; ++j) { v[j] = (m[tid * 16 + j] == 0) ? 1 : 0; s += v[j]; }
    int sc = s;
    for (int d = 1; d < 64; d <<= 1) { int t = __shfl_up(sc, d); if (lane >= d) sc += t; }
    if (lane == 63) ws4[w] = sc;
    __syncthreads();
    if (tid == 0) {
      int acc = 0;
      for (int i = 0; i < 4; ++i) { int t = ws4[i]; ws4[i] = acc; acc += t; }
      cnt[b] = acc;
    }
    __syncthreads();
    int pos = ws4[w] + sc - s;
    int* p = perm + b * 4096;
#pragma unroll
    for (int j = 0; j < 16; ++j) { p[tid * 16 + j] = v[j] ? pos : -1; pos += v[j]; }
  }
}

// ---------------- fused QKV GEMM, 128x128 tile, swapped-operand epilogue ----------------
__global__ __launch_bounds__(256, 2) void k_gemmqkv(
    const short* __restrict__ A, const short* __restrict__ W,
    const float* __restrict__ bq, const float* __restrict__ bk,
    const float* __restrict__ bv, const int* __restrict__ perm,
    short* __restrict__ oq, short* __restrict__ ok, short* __restrict__ ov) {
  __shared__ short Asm[2][128 * 64];
  __shared__ short Bsm[2][128 * 64];
  const int tid = threadIdx.x;
  const int wave = tid >> 6, lane = tid & 63;
  const int lane15 = lane & 15, g = lane >> 4;
  const int wm = wave >> 1, wn = wave & 1;
  const int m0 = blockIdx.x * 128;
  const int n0 = blockIdx.y * 128;

  const char* Ag = (const char*)A + (size_t)m0 * 1024;
  const char* Bg = (const char*)W + (size_t)n0 * 1024;

  f32x4 acc[4][4] = {};

  auto stage = [&](int buf, int kt) {
    const int k0b = kt * 128;
#pragma unroll
    for (int q = 0; q < 4; ++q) {
      int s_ = (wave * 4 + q) * 64 + lane;
      int row = s_ >> 3, ch = s_ & 7;
      gload_lds16(Ag + (size_t)row * 1024 + k0b + (((ch ^ row) & 7) << 4),
                  (char*)&Asm[buf][0] + s_ * 16);
      gload_lds16(Bg + (size_t)row * 1024 + k0b + (((ch ^ row) & 7) << 4),
                  (char*)&Bsm[buf][0] + s_ * 16);
    }
  };

  stage(0, 0);
  asm volatile("s_waitcnt vmcnt(0)" ::: "memory");
  __syncthreads();

  for (int kt = 0; kt < 8; ++kt) {
    const int cur = kt & 1;
    if (kt < 7) stage(cur ^ 1, kt + 1);
#pragma unroll
    for (int kk = 0; kk < 2; ++kk) {
      bf16x8 af[4], bfr[4];
#pragma unroll
      for (int m = 0; m < 4; ++m)
        af[m] = lds_read_swz(&Asm[cur][0], wm * 64 + m * 16 + lane15, kk * 4 + g);
#pragma unroll
      for (int n = 0; n < 4; ++n)
        bfr[n] = lds_read_swz(&Bsm[cur][0], wn * 64 + n * 16 + lane15, kk * 4 + g);
      __builtin_amdgcn_s_setprio(1);
#pragma unroll
      for (int m = 0; m < 4; ++m)
#pragma unroll
        for (int n = 0; n < 4; ++n)
          acc[m][n] = MFMA16(bfr[n], af[m], acc[m][n]);  // swapped: C^T fragment
      __builtin_amdgcn_s_setprio(0);
    }
    asm volatile("s_waitcnt vmcnt(0)" ::: "memory");
    __syncthreads();
  }

  const int mat = blockIdx.y >> 2;
  const float* bptr = (mat == 0) ? bq : (mat == 1) ? bk : bv;
  const int hh = ((n0 & 511) >> 6) + wn;
  const int hb = g >> 1, j4 = (g & 1) * 4;

#pragma unroll
  for (int mf = 0; mf < 4; ++mf) {
    const int rowg = m0 + wm * 64 + mf * 16 + lane15;
    const int b_ = rowg >> 12, sl = rowg & 4095;
    const size_t bh = (size_t)(b_ * 8 + hh);
    int pm_ = 0;
    if (mat != 0) pm_ = perm[b_ * 4096 + sl];
#pragma unroll
    for (int nf = 0; nf < 4; ++nf) {
      const int nn = (n0 & 511) + wn * 64 + nf * 16 + g * 4;
      const float4 b4 = *(const float4*)(bptr + nn);
      const float v0 = acc[mf][nf][0] + b4.x;
      const float v1 = acc[mf][nf][1] + b4.y;
      const float v2 = acc[mf][nf][2] + b4.z;
      const float v3 = acc[mf][nf][3] + b4.w;
      if (mat == 0) {
        short4 s4;
        s4.x = f2b(v0 * QSCALE); s4.y = f2b(v1 * QSCALE);
        s4.z = f2b(v2 * QSCALE); s4.w = f2b(v3 * QSCALE);
        *(short4*)(oq + bh * 262144 +
                   (size_t)(((sl >> 5) * 4 + nf) * 64 + hb * 32 + (sl & 31)) * 8 + j4) = s4;
      } else if (pm_ >= 0) {
        const int t = pm_ >> 6, r = pm_ & 63;
        if (mat == 1) {
          short4 s4;
          s4.x = f2b(v0); s4.y = f2b(v1); s4.z = f2b(v2); s4.w = f2b(v3);
          *(short4*)(ok + bh * 262144 +
                     (size_t)((t * 8 + nf * 2 + (r >> 5)) * 64 + hb * 32 + (r & 31)) * 8 + j4) = s4;
        } else {
          const int mm = (r & ~12) | (((r >> 2) & 1) << 3) | (((r >> 3) & 1) << 2);
          short* base = ov + bh * 262144 +
                        (size_t)((t * 8 + ((mm >> 4) & 3) * 2 + (nf >> 1)) * 64 +
                                 ((mm >> 3) & 1) * 32 + (nf & 1) * 16 + g * 4) * 8 + (mm & 7);
          base[0] = f2b(v0); base[8] = f2b(v1); base[16] = f2b(v2); base[24] = f2b(v3);
        }
      }
    }
  }
}

// ---------------- output projection GEMM, 128x64 tile, grid (64, 8) ----------------
__global__ __launch_bounds__(256, 2) void k_gemmo(
    const short* __restrict__ A, const short* __restrict__ W,
    const float* __restrict__ bias, float* __restrict__ fo) {
  __shared__ short Asm[2][128 * 64];
  __shared__ short Bsm[2][64 * 64];
  const int tid = threadIdx.x;
  const int wave = tid >> 6, lane = tid & 63;
  const int lane15 = lane & 15, g = lane >> 4;
  const int wm = wave >> 1, wn = wave & 1;
  const int m0 = blockIdx.x * 128;
  const int n0 = blockIdx.y * 64;

  const char* Ag = (const char*)A + (size_t)m0 * 1024;
  const char* Bg = (const char*)W + (size_t)n0 * 1024;

  f32x4 acc[4][2] = {};

  auto stage = [&](int buf, int kt) {
    const int k0b = kt * 128;
#pragma unroll
    for (int q = 0; q < 4; ++q) {
      int s_ = (wave * 4 + q) * 64 + lane;
      int row = s_ >> 3, ch = s_ & 7;
      gload_lds16(Ag + (size_t)row * 1024 + k0b + (((ch ^ row) & 7) << 4),
                  (char*)&Asm[buf][0] + s_ * 16);
    }
#pragma unroll
    for (int q = 0; q < 2; ++q) {
      int s_ = (wave * 2 + q) * 64 + lane;
      int row = s_ >> 3, ch = s_ & 7;
      gload_lds16(Bg + (size_t)row * 1024 + k0b + (((ch ^ row) & 7) << 4),
                  (char*)&Bsm[buf][0] + s_ * 16);
    }
  };

  stage(0, 0);
  asm volatile("s_waitcnt vmcnt(0)" ::: "memory");
  __syncthreads();

  for (int kt = 0; kt < 8; ++kt) {
    const int cur = kt & 1;
    if (kt < 7) stage(cur ^ 1, kt + 1);
#pragma unroll
    for (int kk = 0; kk < 2; ++kk) {
      bf16x8 af[4], bfr[2];
#pragma unroll
      for (int m = 0; m < 4; ++m)
        af[m] = lds_read_swz(&Asm[cur][0], wm * 64 + m * 16 + lane15, kk * 4 + g);
#pragma unroll
      for (int n = 0; n < 2; ++n)
        bfr[n] = lds_read_swz(&Bsm[cur][0], wn * 32 + n * 16 + lane15, kk * 4 + g);
      __builtin_amdgcn_s_setprio(1);
#pragma unroll
      for (int m = 0; m < 4; ++m)
#pragma unroll
        for (int n = 0; n < 2; ++n)
          acc[m][n] = MFMA16(bfr[n], af[m], acc[m][n]);  // swapped
      __builtin_amdgcn_s_setprio(0);
    }
    asm volatile("s_waitcnt vmcnt(0)" ::: "memory");
    __syncthreads();
  }

#pragma unroll
  for (int mf = 0; mf < 4; ++mf) {
    const int rowg = m0 + wm * 64 + mf * 16 + lane15;
#pragma unroll
    for (int nf = 0; nf < 2; ++nf) {
      const int cb = n0 + wn * 32 + nf * 16 + g * 4;
      const float4 b4 = *(const float4*)(bias + cb);
      float4 o4;
      o4.x = acc[mf][nf][0] + b4.x;
      o4.y = acc[mf][nf][1] + b4.y;
      o4.z = acc[mf][nf][2] + b4.z;
      o4.w = acc[mf][nf][3] + b4.w;
      *(float4*)(fo + (size_t)rowg * 512 + cb) = o4;
    }
  }
}

// ---------------- flash attention: 2-tile-deep iterations, LDS-staged K/V --------------
// grid 512 (XCD-swizzled); 4 waves x 32 q-rows; KV tiles processed in PAIRS per
// barrier: 2 independent QK chains + 2 exp streams + per-tile PV accumulators give
// per-wave ILP so MFMA-in-flight overlaps the other tile's exp VALU. Fixed-base
// softmax (p = exp2(s), shift cancels in o/l). V' key order bit-swapped (P lane-local).
__global__ __launch_bounds__(256, 2) void k_attn(
    const short* __restrict__ Qp, const short* __restrict__ Kp,
    const short* __restrict__ Vp, const int* __restrict__ cnt,
    short* __restrict__ out) {
  __shared__ short Ks[2][2][8][512];  // [buf][tile-in-pair][fragment][lane*8]
  __shared__ short Vs[2][2][8][512];

  const int tid = threadIdx.x;
  const int wave = tid >> 6, lane = tid & 63;
  const int l31 = lane & 31, h = lane >> 5;
  const int bid = blockIdx.x;
  const int sid = (bid & 7) * 64 + (bid >> 3);
  const int qt = sid & 31, bh = sid >> 5;
  const int b = bh >> 3, hh = bh & 7;
  const int qb = qt * 4 + wave;

  const short* Qg = Qp + (size_t)bh * 262144;
  const short* Kg = Kp + (size_t)bh * 262144;
  const short* Vg = Vp + (size_t)bh * 262144;

  bf16x8 qreg[4];
#pragma unroll
  for (int dk = 0; dk < 4; ++dk)
    qreg[dk] = *(const bf16x8*)(Qg + ((size_t)(qb * 4 + dk) * 64 + lane) * 8);

  const int cn = cnt[b];
  const int nt = max(1, (cn + 63) >> 6);
  const int ntp = (nt + 1) >> 1;  // tile pairs; pad tile fully masked

  auto stage = [&](int buf, int tp) {
#pragma unroll
    for (int q = 0; q < 2; ++q) {
      const int u = wave * 2 + q;
#pragma unroll
      for (int tt = 0; tt < 2; ++tt) {
        const int t = tp * 2 + tt;
        gload_lds16(Kg + ((size_t)(t * 8 + u) * 64 + lane) * 8, &Ks[buf][tt][u][lane * 8]);
        gload_lds16(Vg + ((size_t)(t * 8 + u) * 64 + lane) * 8, &Vs[buf][tt][u][lane * 8]);
      }
    }
  };
  auto ldsK = [&](int buf, int tt, int u) { return *(const bf16x8*)&Ks[buf][tt][u][lane * 8]; };
  auto ldsV = [&](int buf, int tt, int u) { return *(const bf16x8*)&Vs[buf][tt][u][lane * 8]; };

  f32x16 o0a = {}, o0b = {}, o1a = {}, o1b = {};
  float l_ = 0.f;

  stage(0, 0);
  __syncthreads();

  for (int tp = 0; tp < ntp; ++tp) {
    const int cur = tp & 1;
    if (tp + 1 < ntp) stage(cur ^ 1, tp + 1);

    f32x16 sA0 = {}, sA1 = {}, sB0 = {}, sB1 = {};
    __builtin_amdgcn_s_setprio(1);
#pragma unroll
    for (int dk = 0; dk < 4; ++dk) {
      sA0 = MFMA32(ldsK(cur, 0, 2 * dk), qreg[dk], sA0);
      sA1 = MFMA32(ldsK(cur, 0, 2 * dk + 1), qreg[dk], sA1);
    }
#pragma unroll
    for (int dk = 0; dk < 4; ++dk) {
      sB0 = MFMA32(ldsK(cur, 1, 2 * dk), qreg[dk], sB0);
      sB1 = MFMA32(ldsK(cur, 1, 2 * dk + 1), qreg[dk], sB1);
    }
    __builtin_amdgcn_s_setprio(0);

    const int lim0 = cn - (tp * 2) * 64;
    const int lim1 = cn - (tp * 2 + 1) * 64;
    if (lim0 < 64) {
#pragma unroll
      for (int i = 0; i < 16; ++i) {
        const int r0 = (i & 3) + 8 * (i >> 2) + 4 * h;
        if (r0 >= lim0) sA0[i] = -1e30f;
        if (r0 + 32 >= lim0) sA1[i] = -1e30f;
      }
    }
    if (lim1 < 64) {
#pragma unroll
      for (int i = 0; i < 16; ++i) {
        const int r0 = (i & 3) + 8 * (i >> 2) + 4 * h;
        if (r0 >= lim1) sB0[i] = -1e30f;
        if (r0 + 32 >= lim1) sB1[i] = -1e30f;
      }
    }

    // ---- tile 0: exp+pack then PV into a-accumulators ----
    unsigned int w00[8], w01[8];
    float ts0 = 0.f;
#pragma unroll
    for (int j2 = 0; j2 < 8; ++j2) {
      float a0 = exp2fast(sA0[2 * j2]);
      float a1 = exp2fast(sA0[2 * j2 + 1]);
      float b0 = exp2fast(sA1[2 * j2]);
      float b1 = exp2fast(sA1[2 * j2 + 1]);
      ts0 += (a0 + a1) + (b0 + b1);
      asm("v_cvt_pk_bf16_f32 %0, %1, %2" : "=v"(w00[j2]) : "v"(a0), "v"(a1));
      asm("v_cvt_pk_bf16_f32 %0, %1, %2" : "=v"(w01[j2]) : "v"(b0), "v"(b1));
    }
    __builtin_amdgcn_s_setprio(1);
#pragma unroll
    for (int s = 0; s < 4; ++s) {
      const bf16x8 v0 = ldsV(cur, 0, 2 * s);
      const bf16x8 v1 = ldsV(cur, 0, 2 * s + 1);
      const unsigned int* w = (s < 2) ? w00 : w01;
      union PU { u32x4 u; bf16x8 f; } pu;
      pu.u[0] = w[4 * (s & 1) + 0];
      pu.u[1] = w[4 * (s & 1) + 1];
      pu.u[2] = w[4 * (s & 1) + 2];
      pu.u[3] = w[4 * (s & 1) + 3];
      o0a = MFMA32(v0, pu.f, o0a);
      o1a = MFMA32(v1, pu.f, o1a);
    }
    __builtin_amdgcn_s_setprio(0);

    // ---- tile 1: exp+pack then PV into b-accumulators ----
    unsigned int w10[8], w11[8];
    float ts1 = 0.f;
#pragma unroll
    for (int j2 = 0; j2 < 8; ++j2) {
      float a0 = exp2fast(sB0[2 * j2]);
      float a1 = exp2fast(sB0[2 * j2 + 1]);
      float b0 = exp2fast(sB1[2 * j2]);
      float b1 = exp2fast(sB1[2 * j2 + 1]);
      ts1 += (a0 + a1) + (b0 + b1);
      asm("v_cvt_pk_bf16_f32 %0, %1, %2" : "=v"(w10[j2]) : "v"(a0), "v"(a1));
      asm("v_cvt_pk_bf16_f32 %0, %1, %2" : "=v"(w11[j2]) : "v"(b0), "v"(b1));
    }
    l_ += ts0 + ts1;
    __builtin_amdgcn_s_setprio(1);
#pragma unroll
    for (int s = 0; s < 4; ++s) {
      const bf16x8 v0 = ldsV(cur, 1, 2 * s);
      const bf16x8 v1 = ldsV(cur, 1, 2 * s + 1);
      const unsigned int* w = (s < 2) ? w10 : w11;
      union PU { u32x4 u; bf16x8 f; } pu;
      pu.u[0] = w[4 * (s & 1) + 0];
      pu.u[1] = w[4 * (s & 1) + 1];
      pu.u[2] = w[4 * (s & 1) + 2];
      pu.u[3] = w[4 * (s & 1) + 3];
      o0b = MFMA32(v0, pu.f, o0b);
      o1b = MFMA32(v1, pu.f, o1b);
    }
    __builtin_amdgcn_s_setprio(0);

    __syncthreads();  // drains staging loads + releases buf for overwrite
  }

  const f32x16 o0 = o0a + o0b;
  const f32x16 o1 = o1a + o1b;
  l_ += __shfl_xor(l_, 32);
  const float inv = 1.0f / l_;
  short* og = out + (size_t)(b * 4096 + qb * 32 + l31) * 512 + hh * 64;
#pragma unroll
  for (int r2 = 0; r2 < 4; ++r2) {
    {
      const int base = 8 * r2 + 4 * h;
      short4 s4;
      s4.x = f2b(o0[4 * r2 + 0] * inv);
      s4.y = f2b(o0[4 * r2 + 1] * inv);
      s4.z = f2b(o0[4 * r2 + 2] * inv);
      s4.w = f2b(o0[4 * r2 + 3] * inv);
      *(short4*)(og + base) = s4;
    }
    {
      const int base = 32 + 8 * r2 + 4 * h;
      short4 s4;
      s4.x = f2b(o1[4 * r2 + 0] * inv);
      s4.y = f2b(o1[4 * r2 + 1] * inv);
      s4.z = f2b(o1[4 * r2 + 2] * inv);
      s4.w = f2b(o1[4 * r2 + 3] * inv);
      *(short4*)(og + base) = s4;
    }
  }
}

// ---------------- launch ----------------
extern "C" void kernel_launch(void* const* d_in, const int* in_sizes, int n_in,
                              void* d_out, int out_size, void* d_ws, size_t ws_size,
                              hipStream_t stream) {
  const float* x  = (const float*)d_in[0];
  const int* mask = (const int*)d_in[1];
  const float* Wq = (const float*)d_in[2];
  const float* bq = (const float*)d_in[3];
  const float* Wk = (const float*)d_in[4];
  const float* bk = (const float*)d_in[5];
  const float* Wv = (const float*)d_in[6];
  const float* bv = (const float*)d_in[7];
  const float* Wo = (const float*)d_in[8];
  const float* bo = (const float*)d_in[9];
  float* out = (float*)d_out;

  short* xb   = (short*)d_ws;                        // 8192*512 bf16
  short* wt   = xb + (size_t)8192 * 512;             // 4*512*512 bf16
  short* qws  = wt + (size_t)4 * 512 * 512;          // Q' fragment-packed, QSCALE'd
  short* kws  = qws + (size_t)8192 * 512;            // K' fragment-packed, compacted
  short* vws  = kws + (size_t)8192 * 512;            // V' fragment-packed, compacted+bitswap
  short* aout = vws + (size_t)8192 * 512;            // [b*s][512] bf16
  int* perm   = (int*)(aout + (size_t)8192 * 512);   // [b][s]
  int* cntw   = perm + 8192;

  k_prep<<<4354, 256, 0, stream>>>(x, Wq, Wk, Wv, Wo, mask, xb, wt, perm, cntw);
  k_gemmqkv<<<dim3(64, 12), 256, 0, stream>>>(xb, wt, bq, bk, bv, perm, qws, kws, vws);
  k_attn<<<512, 256, 0, stream>>>(qws, kws, vws, cntw, aout);
  k_gemmo<<<dim3(64, 8), 256, 0, stream>>>(aout, wt + (size_t)3 * 512 * 512, bo, out);
}

// Round 10
// 162.822 us; speedup vs baseline: 1.2871x; 1.0067x over previous
//
#include <hip/hip_runtime.h>
#include <hip/hip_bf16.h>
#include <stdint.h>

typedef __attribute__((ext_vector_type(8))) short bf16x8;
typedef __attribute__((ext_vector_type(4))) float f32x4;
typedef __attribute__((ext_vector_type(16))) float f32x16;
typedef __attribute__((ext_vector_type(4))) unsigned int u32x4;

#define MFMA16(a, b, c) __builtin_amdgcn_mfma_f32_16x16x32_bf16(a, b, c, 0, 0, 0)
#define MFMA32(a, b, c) __builtin_amdgcn_mfma_f32_32x32x16_bf16(a, b, c, 0, 0, 0)

constexpr float QSCALE = 0.04419417382415922f * 1.4426950408889634f;  // 1/sqrt(512) * log2(e)

__device__ __forceinline__ void gload_lds16(const void* g, void* l) {
  __builtin_amdgcn_global_load_lds((const __attribute__((address_space(1))) uint32_t*)g,
                                   (__attribute__((address_space(3))) uint32_t*)l, 16, 0, 0);
}
__device__ __forceinline__ bf16x8 lds_read_swz(const short* base, int row, int ch) {
  return *(const bf16x8*)((const char*)base + row * 128 + (((ch ^ row) & 7) << 4));
}
__device__ __forceinline__ short f2b(float f) {
  __hip_bfloat16 h = __float2bfloat16(f);
  return *reinterpret_cast<short*>(&h);
}
__device__ __forceinline__ float exp2fast(float x) {
#if __has_builtin(__builtin_amdgcn_exp2f)
  return __builtin_amdgcn_exp2f(x);
#else
  return exp2f(x);
#endif
}

// ---------------- fused preprocessing: x->bf16 | W transpose->bf16 | mask scan --------
// grid 4354: [0,4096) cvt_x ; [4096,4352) cvt_w ; [4352,4354) scan
__global__ void k_prep(const float* __restrict__ x,
                       const float* __restrict__ wq, const float* __restrict__ wk,
                       const float* __restrict__ wv, const float* __restrict__ wo,
                       const int* __restrict__ mask,
                       short* __restrict__ xb, short* __restrict__ wt,
                       int* __restrict__ perm, int* __restrict__ cnt) {
  __shared__ float tile[64][65];
  __shared__ int ws4[4];
  const int bid = blockIdx.x, tid = threadIdx.x;

  if (bid < 4096) {
    const int i = bid * 256 + tid;
    const float4 v = ((const float4*)x)[i];
    short4 o;
    o.x = f2b(v.x); o.y = f2b(v.y); o.z = f2b(v.z); o.w = f2b(v.w);
    ((short4*)xb)[i] = o;
  } else if (bid < 4352) {
    const int bp = bid - 4096;
    const int mat = bp >> 6;
    const int t6 = bp & 63;
    const int k0 = (t6 >> 3) * 64, n0 = (t6 & 7) * 64;
    const float* w = (mat == 0) ? wq : (mat == 1) ? wk : (mat == 2) ? wv : wo;
    const int c = tid & 63, r4 = tid >> 6;
#pragma unroll
    for (int p = 0; p < 16; ++p) {
      const int r = p * 4 + r4;
      tile[r][c] = w[(k0 + r) * 512 + n0 + c];
    }
    __syncthreads();
#pragma unroll
    for (int p = 0; p < 16; ++p) {
      const int r = p * 4 + r4;
      wt[mat * 262144 + (n0 + r) * 512 + k0 + c] = f2b(tile[c][r]);
    }
  } else {
    const int b = bid - 4352;
    const int lane = tid & 63, w = tid >> 6;
    const int* m = mask + b * 4096;
    int v[16], s = 0;
#pragma unroll
    for (int j = 0; j < 16; ++j) { v[j] = (m[tid * 16 + j] == 0) ? 1 : 0; s += v[j]; }
    int sc = s;
    for (int d = 1; d < 64; d <<= 1) { int t = __shfl_up(sc, d); if (lane >= d) sc += t; }
    if (lane == 63) ws4[w] = sc;
    __syncthreads();
    if (tid == 0) {
      int acc = 0;
      for (int i = 0; i < 4; ++i) { int t = ws4[i]; ws4[i] = acc; acc += t; }
      cnt[b] = acc;
    }
    __syncthreads();
    int pos = ws4[w] + sc - s;
    int* p = perm + b * 4096;
#pragma unroll
    for (int j = 0; j < 16; ++j) { p[tid * 16 + j] = v[j] ? pos : -1; pos += v[j]; }
  }
}

// ---------------- fused QKV GEMM, 128x128 tile, swapped-operand epilogue ----------------
__global__ __launch_bounds__(256, 2) void k_gemmqkv(
    const short* __restrict__ A, const short* __restrict__ W,
    const float* __restrict__ bq, const float* __restrict__ bk,
    const float* __restrict__ bv, const int* __restrict__ perm,
    short* __restrict__ oq, short* __restrict__ ok, short* __restrict__ ov) {
  __shared__ short Asm[2][128 * 64];
  __shared__ short Bsm[2][128 * 64];
  const int tid = threadIdx.x;
  const int wave = tid >> 6, lane = tid & 63;
  const int lane15 = lane & 15, g = lane >> 4;
  const int wm = wave >> 1, wn = wave & 1;
  const int m0 = blockIdx.x * 128;
  const int n0 = blockIdx.y * 128;

  const char* Ag = (const char*)A + (size_t)m0 * 1024;
  const char* Bg = (const char*)W + (size_t)n0 * 1024;

  f32x4 acc[4][4] = {};

  auto stage = [&](int buf, int kt) {
    const int k0b = kt * 128;
#pragma unroll
    for (int q = 0; q < 4; ++q) {
      int s_ = (wave * 4 + q) * 64 + lane;
      int row = s_ >> 3, ch = s_ & 7;
      gload_lds16(Ag + (size_t)row * 1024 + k0b + (((ch ^ row) & 7) << 4),
                  (char*)&Asm[buf][0] + s_ * 16);
      gload_lds16(Bg + (size_t)row * 1024 + k0b + (((ch ^ row) & 7) << 4),
                  (char*)&Bsm[buf][0] + s_ * 16);
    }
  };

  stage(0, 0);
  asm volatile("s_waitcnt vmcnt(0)" ::: "memory");
  __syncthreads();

  for (int kt = 0; kt < 8; ++kt) {
    const int cur = kt & 1;
    if (kt < 7) stage(cur ^ 1, kt + 1);
#pragma unroll
    for (int kk = 0; kk < 2; ++kk) {
      bf16x8 af[4], bfr[4];
#pragma unroll
      for (int m = 0; m < 4; ++m)
        af[m] = lds_read_swz(&Asm[cur][0], wm * 64 + m * 16 + lane15, kk * 4 + g);
#pragma unroll
      for (int n = 0; n < 4; ++n)
        bfr[n] = lds_read_swz(&Bsm[cur][0], wn * 64 + n * 16 + lane15, kk * 4 + g);
#pragma unroll
      for (int m = 0; m < 4; ++m)
#pragma unroll
        for (int n = 0; n < 4; ++n)
          acc[m][n] = MFMA16(bfr[n], af[m], acc[m][n]);  // swapped: C^T fragment
    }
    asm volatile("s_waitcnt vmcnt(0)" ::: "memory");
    __syncthreads();
  }

  const int mat = blockIdx.y >> 2;
  const float* bptr = (mat == 0) ? bq : (mat == 1) ? bk : bv;
  const int hh = ((n0 & 511) >> 6) + wn;
  const int hb = g >> 1, j4 = (g & 1) * 4;

#pragma unroll
  for (int mf = 0; mf < 4; ++mf) {
    const int rowg = m0 + wm * 64 + mf * 16 + lane15;
    const int b_ = rowg >> 12, sl = rowg & 4095;
    const size_t bh = (size_t)(b_ * 8 + hh);
    int pm_ = 0;
    if (mat != 0) pm_ = perm[b_ * 4096 + sl];
#pragma unroll
    for (int nf = 0; nf < 4; ++nf) {
      const int nn = (n0 & 511) + wn * 64 + nf * 16 + g * 4;
      const float4 b4 = *(const float4*)(bptr + nn);
      const float v0 = acc[mf][nf][0] + b4.x;
      const float v1 = acc[mf][nf][1] + b4.y;
      const float v2 = acc[mf][nf][2] + b4.z;
      const float v3 = acc[mf][nf][3] + b4.w;
      if (mat == 0) {
        short4 s4;
        s4.x = f2b(v0 * QSCALE); s4.y = f2b(v1 * QSCALE);
        s4.z = f2b(v2 * QSCALE); s4.w = f2b(v3 * QSCALE);
        *(short4*)(oq + bh * 262144 +
                   (size_t)(((sl >> 5) * 4 + nf) * 64 + hb * 32 + (sl & 31)) * 8 + j4) = s4;
      } else if (pm_ >= 0) {
        const int t = pm_ >> 6, r = pm_ & 63;
        if (mat == 1) {
          short4 s4;
          s4.x = f2b(v0); s4.y = f2b(v1); s4.z = f2b(v2); s4.w = f2b(v3);
          *(short4*)(ok + bh * 262144 +
                     (size_t)((t * 8 + nf * 2 + (r >> 5)) * 64 + hb * 32 + (r & 31)) * 8 + j4) = s4;
        } else {
          const int mm = (r & ~12) | (((r >> 2) & 1) << 3) | (((r >> 3) & 1) << 2);
          short* base = ov + bh * 262144 +
                        (size_t)((t * 8 + ((mm >> 4) & 3) * 2 + (nf >> 1)) * 64 +
                                 ((mm >> 3) & 1) * 32 + (nf & 1) * 16 + g * 4) * 8 + (mm & 7);
          base[0] = f2b(v0); base[8] = f2b(v1); base[16] = f2b(v2); base[24] = f2b(v3);
        }
      }
    }
  }
}

// ---------------- output projection GEMM, 128x64 tile, grid (64, 8) ----------------
__global__ __launch_bounds__(256, 2) void k_gemmo(
    const short* __restrict__ A, const short* __restrict__ W,
    const float* __restrict__ bias, float* __restrict__ fo) {
  __shared__ short Asm[2][128 * 64];
  __shared__ short Bsm[2][64 * 64];
  const int tid = threadIdx.x;
  const int wave = tid >> 6, lane = tid & 63;
  const int lane15 = lane & 15, g = lane >> 4;
  const int wm = wave >> 1, wn = wave & 1;
  const int m0 = blockIdx.x * 128;
  const int n0 = blockIdx.y * 64;

  const char* Ag = (const char*)A + (size_t)m0 * 1024;
  const char* Bg = (const char*)W + (size_t)n0 * 1024;

  f32x4 acc[4][2] = {};

  auto stage = [&](int buf, int kt) {
    const int k0b = kt * 128;
#pragma unroll
    for (int q = 0; q < 4; ++q) {
      int s_ = (wave * 4 + q) * 64 + lane;
      int row = s_ >> 3, ch = s_ & 7;
      gload_lds16(Ag + (size_t)row * 1024 + k0b + (((ch ^ row) & 7) << 4),
                  (char*)&Asm[buf][0] + s_ * 16);
    }
#pragma unroll
    for (int q = 0; q < 2; ++q) {
      int s_ = (wave * 2 + q) * 64 + lane;
      int row = s_ >> 3, ch = s_ & 7;
      gload_lds16(Bg + (size_t)row * 1024 + k0b + (((ch ^ row) & 7) << 4),
                  (char*)&Bsm[buf][0] + s_ * 16);
    }
  };

  stage(0, 0);
  asm volatile("s_waitcnt vmcnt(0)" ::: "memory");
  __syncthreads();

  for (int kt = 0; kt < 8; ++kt) {
    const int cur = kt & 1;
    if (kt < 7) stage(cur ^ 1, kt + 1);
#pragma unroll
    for (int kk = 0; kk < 2; ++kk) {
      bf16x8 af[4], bfr[2];
#pragma unroll
      for (int m = 0; m < 4; ++m)
        af[m] = lds_read_swz(&Asm[cur][0], wm * 64 + m * 16 + lane15, kk * 4 + g);
#pragma unroll
      for (int n = 0; n < 2; ++n)
        bfr[n] = lds_read_swz(&Bsm[cur][0], wn * 32 + n * 16 + lane15, kk * 4 + g);
#pragma unroll
      for (int m = 0; m < 4; ++m)
#pragma unroll
        for (int n = 0; n < 2; ++n)
          acc[m][n] = MFMA16(bfr[n], af[m], acc[m][n]);  // swapped
    }
    asm volatile("s_waitcnt vmcnt(0)" ::: "memory");
    __syncthreads();
  }

#pragma unroll
  for (int mf = 0; mf < 4; ++mf) {
    const int rowg = m0 + wm * 64 + mf * 16 + lane15;
#pragma unroll
    for (int nf = 0; nf < 2; ++nf) {
      const int cb = n0 + wn * 32 + nf * 16 + g * 4;
      const float4 b4 = *(const float4*)(bias + cb);
      float4 o4;
      o4.x = acc[mf][nf][0] + b4.x;
      o4.y = acc[mf][nf][1] + b4.y;
      o4.z = acc[mf][nf][2] + b4.z;
      o4.w = acc[mf][nf][3] + b4.w;
      *(float4*)(fo + (size_t)rowg * 512 + cb) = o4;
    }
  }
}

// ---------------- flash attention: 4-slot ring, counted vmcnt, no drain ----------------
// grid 512 (XCD-swizzled); 4 waves x 32 q-rows; 64-key tiles.
// Per window: issue stage(t+2) -> s_waitcnt vmcnt(8) (waits ONLY tile t's 4 loads,
// issued 2 windows ago) -> raw s_barrier (no counter drain) -> compute tile t.
// Slot safety: slot s is rewritten for tile t+4 at window t+2, after barrier(t+1),
// which every wave passes only after finishing compute(t). Waves drift freely ->
// cross-wave MFMA/VALU overlap. Fixed-base softmax (p=exp2(s), shift cancels in o/l);
// PV accumulators split by parity (4 chains of depth 2).
__global__ __launch_bounds__(256, 2) void k_attn(
    const short* __restrict__ Qp, const short* __restrict__ Kp,
    const short* __restrict__ Vp, const int* __restrict__ cnt,
    short* __restrict__ out) {
  __shared__ short Ks[4][8][512];  // [slot][fragment][lane*8]
  __shared__ short Vs[4][8][512];

  const int tid = threadIdx.x;
  const int wave = tid >> 6, lane = tid & 63;
  const int l31 = lane & 31, h = lane >> 5;
  const int bid = blockIdx.x;
  const int sid = (bid & 7) * 64 + (bid >> 3);  // XCD-bijective swizzle (512 = 8*64)
  const int qt = sid & 31, bh = sid >> 5;
  const int b = bh >> 3, hh = bh & 7;
  const int qb = qt * 4 + wave;

  const short* Qg = Qp + (size_t)bh * 262144;
  const short* Kg = Kp + (size_t)bh * 262144;
  const short* Vg = Vp + (size_t)bh * 262144;

  bf16x8 qreg[4];
#pragma unroll
  for (int dk = 0; dk < 4; ++dk)
    qreg[dk] = *(const bf16x8*)(Qg + ((size_t)(qb * 4 + dk) * 64 + lane) * 8);

  const int cn = cnt[b];
  const int nt = max(1, (cn + 63) >> 6);

  auto stage = [&](int slot, int t) {
#pragma unroll
    for (int q = 0; q < 2; ++q) {
      const int u = wave * 2 + q;  // each wave stages 2 K + 2 V fragments
      gload_lds16(Kg + ((size_t)(t * 8 + u) * 64 + lane) * 8, &Ks[slot][u][lane * 8]);
      gload_lds16(Vg + ((size_t)(t * 8 + u) * 64 + lane) * 8, &Vs[slot][u][lane * 8]);
    }
  };
  auto ldsK = [&](int slot, int u) { return *(const bf16x8*)&Ks[slot][u][lane * 8]; };
  auto ldsV = [&](int slot, int u) { return *(const bf16x8*)&Vs[slot][u][lane * 8]; };

  f32x16 o0x = {}, o0y = {}, o1x = {}, o1y = {};
  float l_ = 0.f;

  stage(0, 0);
  stage(1, min(1, nt - 1));

  for (int t = 0; t < nt; ++t) {
    const int cur = t & 3;
    stage((t + 2) & 3, min(t + 2, nt - 1));  // clamped src; clamped slots are never read
    asm volatile("s_waitcnt vmcnt(8)" ::: "memory");  // oldest 4 (tile t) retired
    __builtin_amdgcn_sched_barrier(0);
    __builtin_amdgcn_s_barrier();                     // no counter drain
    __builtin_amdgcn_sched_barrier(0);

    f32x16 s0v = {}, s1v = {};
    __builtin_amdgcn_s_setprio(1);
#pragma unroll
    for (int dk = 0; dk < 4; ++dk) {
      s0v = MFMA32(ldsK(cur, 2 * dk), qreg[dk], s0v);
      s1v = MFMA32(ldsK(cur, 2 * dk + 1), qreg[dk], s1v);
    }
    __builtin_amdgcn_s_setprio(0);

    const int lim = cn - t * 64;
    if (lim < 64) {
#pragma unroll
      for (int i = 0; i < 16; ++i) {
        const int r0 = (i & 3) + 8 * (i >> 2) + 4 * h;
        if (r0 >= lim) s0v[i] = -1e30f;
        if (r0 + 32 >= lim) s1v[i] = -1e30f;
      }
    }

    unsigned int wA[8], wB[8];
    float ts = 0.f;
#pragma unroll
    for (int j2 = 0; j2 < 8; ++j2) {
      float a0 = exp2fast(s0v[2 * j2]);
      float a1 = exp2fast(s0v[2 * j2 + 1]);
      float b0 = exp2fast(s1v[2 * j2]);
      float b1 = exp2fast(s1v[2 * j2 + 1]);
      ts += (a0 + a1) + (b0 + b1);
      asm("v_cvt_pk_bf16_f32 %0, %1, %2" : "=v"(wA[j2]) : "v"(a0), "v"(a1));
      asm("v_cvt_pk_bf16_f32 %0, %1, %2" : "=v"(wB[j2]) : "v"(b0), "v"(b1));
    }
    l_ += ts;

    __builtin_amdgcn_s_setprio(1);
#pragma unroll
    for (int s = 0; s < 4; ++s) {
      const bf16x8 v0 = ldsV(cur, 2 * s);
      const bf16x8 v1 = ldsV(cur, 2 * s + 1);
      const unsigned int* w = (s < 2) ? wA : wB;
      union PU { u32x4 u; bf16x8 f; } pu;
      pu.u[0] = w[4 * (s & 1) + 0];
      pu.u[1] = w[4 * (s & 1) + 1];
      pu.u[2] = w[4 * (s & 1) + 2];
      pu.u[3] = w[4 * (s & 1) + 3];
      if (s & 1) {
        o0y = MFMA32(v0, pu.f, o0y);
        o1y = MFMA32(v1, pu.f, o1y);
      } else {
        o0x = MFMA32(v0, pu.f, o0x);
        o1x = MFMA32(v1, pu.f, o1x);
      }
    }
    __builtin_amdgcn_s_setprio(0);
  }

  const f32x16 o0 = o0x + o0y;
  const f32x16 o1 = o1x + o1y;
  l_ += __shfl_xor(l_, 32);
  const float inv = 1.0f / l_;
  short* og = out + (size_t)(b * 4096 + qb * 32 + l31) * 512 + hh * 64;
#pragma unroll
  for (int r2 = 0; r2 < 4; ++r2) {
    {
      const int base = 8 * r2 + 4 * h;
      short4 s4;
      s4.x = f2b(o0[4 * r2 + 0] * inv);
      s4.y = f2b(o0[4 * r2 + 1] * inv);
      s4.z = f2b(o0[4 * r2 + 2] * inv);
      s4.w = f2b(o0[4 * r2 + 3] * inv);
      *(short4*)(og + base) = s4;
    }
    {
      const int base = 32 + 8 * r2 + 4 * h;
      short4 s4;
      s4.x = f2b(o1[4 * r2 + 0] * inv);
      s4.y = f2b(o1[4 * r2 + 1] * inv);
      s4.z = f2b(o1[4 * r2 + 2] * inv);
      s4.w = f2b(o1[4 * r2 + 3] * inv);
      *(short4*)(og + base) = s4;
    }
  }
}

// ---------------- launch ----------------
extern "C" void kernel_launch(void* const* d_in, const int* in_sizes, int n_in,
                              void* d_out, int out_size, void* d_ws, size_t ws_size,
                              hipStream_t stream) {
  const float* x  = (const float*)d_in[0];
  const int* mask = (const int*)d_in[1];
  const float* Wq = (const float*)d_in[2];
  const float* bq = (const float*)d_in[3];
  const float* Wk = (const float*)d_in[4];
  const float* bk = (const float*)d_in[5];
  const float* Wv = (const float*)d_in[6];
  const float* bv = (const float*)d_in[7];
  const float* Wo = (const float*)d_in[8];
  const float* bo = (const float*)d_in[9];
  float* out = (float*)d_out;

  short* xb   = (short*)d_ws;                        // 8192*512 bf16
  short* wt   = xb + (size_t)8192 * 512;             // 4*512*512 bf16
  short* qws  = wt + (size_t)4 * 512 * 512;          // Q' fragment-packed, QSCALE'd
  short* kws  = qws + (size_t)8192 * 512;            // K' fragment-packed, compacted
  short* vws  = kws + (size_t)8192 * 512;            // V' fragment-packed, compacted+bitswap
  short* aout = vws + (size_t)8192 * 512;            // [b*s][512] bf16
  int* perm   = (int*)(aout + (size_t)8192 * 512);   // [b][s]
  int* cntw   = perm + 8192;

  k_prep<<<4354, 256, 0, stream>>>(x, Wq, Wk, Wv, Wo, mask, xb, wt, perm, cntw);
  k_gemmqkv<<<dim3(64, 12), 256, 0, stream>>>(xb, wt, bq, bk, bv, perm, qws, kws, vws);
  k_attn<<<512, 256, 0, stream>>>(qws, kws, vws, cntw, aout);
  k_gemmo<<<dim3(64, 8), 256, 0, stream>>>(aout, wt + (size_t)3 * 512 * 512, bo, out);
}